// Round 8
// baseline (286.993 us; speedup 1.0000x reference)
//
#include <hip/hip_runtime.h>
#include <cstddef>

// ButterFlyNet2D IDFT forward. Split-bf16 MFMA (3-pass: Whi*Yhi + Whi*Ylo + Wlo*Yhi).
// Activations: ONE u32 per element = packed (hi bf16 | lo bf16<<16).
//   Plane layout A[gy][gx][i][k][l][b][p][q] -> per block contiguous Y[256][Nb].
// R8: (1) rec kernels: double-buffered LDS Y tile -> ONE lgkm-only barrier per
// K-step; (2) fused kernel: W5/W4 prefetch issued BEFORE the MFMA cluster so
// in-flight time ~2 clusters ~ HBM latency; W5 chunks 0/1 pre-issued from
// stage-1's tail; (3) stage-2 LDS windows double-buffered (one barrier per kw).

typedef unsigned int  u32;
typedef unsigned short u16;
typedef __attribute__((ext_vector_type(8))) short bf16x8;
typedef __attribute__((ext_vector_type(4))) float f32x4;

#define PLANE 16777216   // elements per activation buffer

__device__ inline u16 bf16_rn(float x) {
    u32 u = __builtin_bit_cast(u32, x);
    u32 r = (u + 0x7FFFu + ((u >> 16) & 1u)) >> 16;
    return (u16)r;
}
__device__ inline float bf16_to_f(u16 h) {
    u32 u = ((u32)h) << 16;
    return __builtin_bit_cast(float, u);
}
__device__ inline u32 pack_split(float v) {
    const u16 h = bf16_rn(v);
    const u16 l = bf16_rn(v - bf16_to_f(h));
    return (u32)h | ((u32)l << 16);
}
// LDS-only barrier: drains ds ops, leaves global loads (vmcnt) in flight.
__device__ inline void bar_lds() {
    asm volatile("s_waitcnt lgkmcnt(0)\n\ts_barrier" ::: "memory");
}

// ---------------- weight pre-convert (layers 1-3, one launch) ----------------
__global__ __launch_bounds__(256)
void wconv_all_kernel(const float* __restrict__ s1, const float* __restrict__ s2,
                      const float* __restrict__ s3,
                      u16* __restrict__ d1, u16* __restrict__ d2, u16* __restrict__ d3) {
    const int i = blockIdx.x * 256 + threadIdx.x;   // 8-elem group, 688128 total
    const float* s; u16 *dh, *dl; int off;
    if (i < 32768)        { s = s1; dh = d1; dl = d1 + 262144;  off = i; }
    else if (i < 163840)  { s = s2; dh = d2; dl = d2 + 1048576; off = i - 32768; }
    else                  { s = s3; dh = d3; dl = d3 + 4194304; off = i - 163840; }
    const float4 a = *(const float4*)(s + 8 * off);
    const float4 b = *(const float4*)(s + 8 * off + 4);
    union { bf16x8 v; u16 u[8]; } H, L;
    const float f[8] = {a.x, a.y, a.z, a.w, b.x, b.y, b.z, b.w};
#pragma unroll
    for (int e = 0; e < 8; ++e) {
        const u16 h = bf16_rn(f[e]);
        H.u[e] = h;
        L.u[e] = bf16_rn(f[e] - bf16_to_f(h));
    }
    *(bf16x8*)(dh + 8 * off) = H.v;
    *(bf16x8*)(dl + 8 * off) = L.v;
}

// ---------------- Layer 0: x read once, 128 outputs per thread ----------------
__global__ __launch_bounds__(256)
void layer0_kernel(const float* __restrict__ xr, const float* __restrict__ xi,
                   const float* __restrict__ w0, const float* __restrict__ b0,
                   u32* __restrict__ A1) {
    __shared__ float w0s[128][16];
    __shared__ float b0s[128];
    const int og  = blockIdx.y;             // 0/1: o = og*128 + j
    const int tid = threadIdx.x;
    {
        const int row = tid >> 1, half = tid & 1;
        const float4 wa = *(const float4*)(w0 + (og * 128 + row) * 16 + half * 8);
        const float4 wb = *(const float4*)(w0 + (og * 128 + row) * 16 + half * 8 + 4);
        *(float4*)&w0s[row][half * 8]     = wa;
        *(float4*)&w0s[row][half * 8 + 4] = wb;
        if (tid < 128) b0s[tid] = b0[og * 128 + tid];
    }
    __syncthreads();

    const int n = blockIdx.x * 256 + tid;   // output pixel: b*1024 + p*32 + q
    const int b = n >> 10, p = (n >> 5) & 31, q = n & 31;
    float xs[16];
#pragma unroll
    for (int k = 0; k < 2; ++k) {
        const float2 vr = *(const float2*)(xr + b * 4096 + (2 * p + k) * 64 + 2 * q);
        const float2 vi = *(const float2*)(xi + b * 4096 + (2 * p + k) * 64 + 2 * q);
        xs[0  + k * 2 + 0] = fmaxf(vr.x, 0.f);  xs[0  + k * 2 + 1] = fmaxf(vr.y, 0.f);
        xs[4  + k * 2 + 0] = fmaxf(vi.x, 0.f);  xs[4  + k * 2 + 1] = fmaxf(vi.y, 0.f);
        xs[8  + k * 2 + 0] = fmaxf(-vr.x, 0.f); xs[8  + k * 2 + 1] = fmaxf(-vr.y, 0.f);
        xs[12 + k * 2 + 0] = fmaxf(-vi.x, 0.f); xs[12 + k * 2 + 1] = fmaxf(-vi.y, 0.f);
    }
    const int kp = p & 1, lp = q & 1, pp = p >> 1, qp = q >> 1;
    const size_t pixoff = (size_t)(b * 256 + pp * 16 + qp);
#pragma unroll
    for (int j = 0; j < 128; ++j) {
        float acc = b0s[j];
#pragma unroll
        for (int e = 0; e < 16; ++e) acc = fmaf(xs[e], w0s[j][e], acc);
        acc = fmaxf(acc, 0.f);
        const int o = og * 128 + j;
        const int gy = o >> 7, gx = (o >> 6) & 1, c = o & 63;
        const size_t flat = (size_t)((((gy * 2 + gx) * 64 + c) * 2 + kp) * 2 + lp) * (64 * 256)
                          + pixoff;
        A1[flat] = pack_split(acc);
    }
}

// ------- Recursion layers 1..3 : split-bf16 MFMA, W direct, LDS dbuf -------
template<int NT>
__global__ __launch_bounds__(256, 2)
void rec_mfma_kernel(const u32* __restrict__ Yg,
                     const u16* __restrict__ Whi_g, const u16* __restrict__ Wlo_g,
                     const float* __restrict__ bias, u32* __restrict__ Aout,
                     const int lgG, const int lgS2) {
    constexpr int NF  = NT / 16;
    constexpr int LD  = 40;
    constexpr int NCP = NT / 2;
    constexpr int RPT = 32 / (256 / NCP);

    __shared__ u16 Yhi_s[2][NT * LD];
    __shared__ u16 Ylo_s[2][NT * LD];

    const int G  = 1 << lgG;
    const int S2 = 1 << lgS2;
    const int Nb = 64 << (2 * lgS2);

    // XCD-chunked swizzle: keep all n-tiles of a block on one XCD (W L2 reuse)
    int bid, nt;
    const int nBid = G * G, NTILES = gridDim.x;
    if (nBid >= 8) {
        const int h = blockIdx.z * NTILES + blockIdx.x;
        const int xcd = h & 7, j = h >> 3, per = nBid >> 3;
        bid = xcd * per + j / NTILES;
        nt  = j % NTILES;
    } else { bid = blockIdx.z; nt = blockIdx.x; }

    const size_t wbase = (size_t)bid * 65536;
    const u32* Yblk = Yg + (size_t)bid * 256 * (size_t)Nb + (size_t)nt * NT;

    const int tid = threadIdx.x, wave = tid >> 6, lane = tid & 63;
    const int l16 = lane & 15, lk = lane >> 4;
    const int cp = tid % NCP, rg = tid / NCP;
    const int col0 = cp * 2, trow = rg * RPT;

    f32x4 acc[4][NF];
#pragma unroll
    for (int m = 0; m < 4; ++m)
#pragma unroll
        for (int n = 0; n < NF; ++n)
            acc[m][n] = (f32x4){0.f, 0.f, 0.f, 0.f};

    uint2  yreg[2][RPT];
    bf16x8 wh[4], wl[4];

    auto loadY = [&](int ybuf, int k0) {
#pragma unroll
        for (int r = 0; r < RPT; ++r)
            yreg[ybuf][r] = *(const uint2*)(Yblk + (size_t)(k0 + trow + r) * Nb + col0);
    };
    auto loadWpre = [&](int k0) {
#pragma unroll
        for (int m = 0; m < 4; ++m) {
            const size_t off = wbase + (size_t)(wave * 64 + m * 16 + l16) * 256 + k0 + lk * 8;
            wh[m] = *(const bf16x8*)(Whi_g + off);
            wl[m] = *(const bf16x8*)(Wlo_g + off);
        }
    };
    // deinterleave yreg[ybuf] and stage into LDS buffer sbuf
    auto prepstage = [&](int ybuf, int sbuf) {
        u32 yhw[2][RPT / 2], ylw[2][RPT / 2];
#pragma unroll
        for (int c = 0; c < 2; ++c)
#pragma unroll
            for (int j2 = 0; j2 < RPT / 2; ++j2) {
                const u32 a = c ? yreg[ybuf][2 * j2].y     : yreg[ybuf][2 * j2].x;
                const u32 b = c ? yreg[ybuf][2 * j2 + 1].y : yreg[ybuf][2 * j2 + 1].x;
                yhw[c][j2] = (a & 0xFFFFu) | (b << 16);
                ylw[c][j2] = (a >> 16)     | (b & 0xFFFF0000u);
            }
#pragma unroll
        for (int c = 0; c < 2; ++c) {
            if constexpr (RPT == 8) {
                *(uint4*)&Yhi_s[sbuf][(col0 + c) * LD + trow] = make_uint4(yhw[c][0], yhw[c][1], yhw[c][2], yhw[c][3]);
                *(uint4*)&Ylo_s[sbuf][(col0 + c) * LD + trow] = make_uint4(ylw[c][0], ylw[c][1], ylw[c][2], ylw[c][3]);
            } else {
                *(uint2*)&Yhi_s[sbuf][(col0 + c) * LD + trow] = make_uint2(yhw[c][0], yhw[c][1]);
                *(uint2*)&Ylo_s[sbuf][(col0 + c) * LD + trow] = make_uint2(ylw[c][0], ylw[c][1]);
            }
        }
    };

    // prologue: yreg0<-k0, yreg1<-k32; stage k0 into buf0; refill yreg0<-k64
    loadY(0, 0); loadY(1, 32);
    prepstage(0, 0);
    loadY(0, 64);

#pragma unroll
    for (int it = 0; it < 8; ++it) {
        const int k0 = it * 32;
        const int sb = it & 1;
        loadWpre(k0);                       // this iter's A-frags (L2-hot)
        bar_lds();                          // buf[sb] visible; buf[sb^1] reads done
        if (it + 1 < 8) prepstage((it + 1) & 1, sb ^ 1);       // stage NEXT tile
        if (it + 3 < 8) loadY((it + 1) & 1, 32 * (it + 3));    // refill slot
        __builtin_amdgcn_s_setprio(1);
#pragma unroll
        for (int n = 0; n < NF; ++n) {
            const int ccol = n * 16 + l16;
            const bf16x8 bhi = *(const bf16x8*)&Yhi_s[sb][ccol * LD + 8 * lk];
            const bf16x8 blo = *(const bf16x8*)&Ylo_s[sb][ccol * LD + 8 * lk];
#pragma unroll
            for (int m = 0; m < 4; ++m)
                acc[m][n] = __builtin_amdgcn_mfma_f32_16x16x32_bf16(wh[m], bhi, acc[m][n], 0, 0, 0);
#pragma unroll
            for (int m = 0; m < 4; ++m)
                acc[m][n] = __builtin_amdgcn_mfma_f32_16x16x32_bf16(wh[m], blo, acc[m][n], 0, 0, 0);
#pragma unroll
            for (int m = 0; m < 4; ++m)
                acc[m][n] = __builtin_amdgcn_mfma_f32_16x16x32_bf16(wl[m], bhi, acc[m][n], 0, 0, 0);
        }
        __builtin_amdgcn_s_setprio(0);
    }

    // ---- epilogue: bias + relu + packed scatter to child blocks ----
    const int gy = bid >> lgG, gx = bid & (G - 1);
    const int NS2 = S2 >> 1;
#pragma unroll
    for (int m = 0; m < 4; ++m) {
#pragma unroll
        for (int r = 0; r < 4; ++r) {
            const int oc = wave * 64 + m * 16 + lk * 4 + r;   // C/D: row=(lane>>4)*4+reg
            const float bi = bias[(size_t)bid * 256 + oc];
            const int yl = oc >> 7, xl = (oc >> 6) & 1, cch = oc & 63;
            const int cy = 2 * gy + yl, cx = 2 * gx + xl;
            const size_t base = (size_t)((cy * (2 * G) + cx) * 64 + cch);
#pragma unroll
            for (int n = 0; n < NF; ++n) {
                const float v = fmaxf(acc[m][n][r] + bi, 0.f);
                const int ng = nt * NT + n * 16 + l16;        // C/D: col=lane&15
                const int b   = ng >> (2 * lgS2);
                const int rem = ng & ((1 << (2 * lgS2)) - 1);
                const int p = rem >> lgS2, q = rem & (S2 - 1);
                const size_t flat = ((base * 2 + (p & 1)) * 2 + (q & 1)) * (size_t)(64 * NS2 * NS2)
                                  + (size_t)(b * NS2 * NS2 + (p >> 1) * NS2 + (q >> 1));
                Aout[flat] = pack_split(v);
            }
        }
    }
}

// ---------------- Fused L4 + L5 + final ----------------
// One wg per L5 block. Stage-1: T[64][256] = relu(b4 + W4slice . Y4), all
// operands direct global->register, prefetch issued BEFORE MFMA clusters.
// Stage-2: L5 GEMM via double-buffered LDS K-windows; W5 depth-2 with loads
// issued before MFMA. Final 1x1 fused in epilogue.
__global__ __launch_bounds__(256, 2)
void rec45_final_kernel(const u32* __restrict__ Yg, const float* __restrict__ W4,
                        const float* __restrict__ b4, const float* __restrict__ W5,
                        const float* __restrict__ b5, const float* __restrict__ wf,
                        const float* __restrict__ bff, float* __restrict__ out) {
    constexpr int LDW = 72;                 // window row stride (u16)
    __shared__ u16 Whi_w[2][64 * LDW];
    __shared__ u16 Wlo_w[2][64 * LDW];

    const int h = blockIdx.x;
    const int parent = ((h >> 5) << 3) | (h & 7);   // 0..255 = pgy*16+pgx
    const int child  = (h >> 3) & 3;
    const int pgy = parent >> 4, pgx = parent & 15;
    const int cy = 2 * pgy + (child >> 1), cx = 2 * pgx + (child & 1);
    const int bid5 = cy * 32 + cx;
    const int ocbase = child * 64;

    const u32* Yblk  = Yg + (size_t)parent * 65536;
    const float* W4s = W4 + (size_t)parent * 65536 + (size_t)ocbase * 256;
    const float* W5b = W5 + (size_t)bid5 * 65536;

    const int tid = threadIdx.x, wave = tid >> 6, lane = tid & 63;
    const int l16 = lane & 15, lk = lane >> 4;

    f32x4 acc1[4][4];
#pragma unroll
    for (int m = 0; m < 4; ++m)
#pragma unroll
        for (int n = 0; n < 4; ++n)
            acc1[m][n] = (f32x4){0.f, 0.f, 0.f, 0.f};

    u32    yf[2][4][8];
    float4 wv[2][8];
    bf16x8 wh[4], wl[4];

    auto loadY = [&](int buf, int k0) {
#pragma unroll
        for (int n = 0; n < 4; ++n)
#pragma unroll
            for (int j = 0; j < 8; ++j)
                yf[buf][n][j] = Yblk[(size_t)(k0 + 8 * lk + j) * 256 + wave * 64 + n * 16 + l16];
    };
    auto loadW4 = [&](int buf, int k0) {
#pragma unroll
        for (int m = 0; m < 4; ++m) {
            const float* p = W4s + (size_t)(m * 16 + l16) * 256 + k0 + lk * 8;
            wv[buf][2 * m]     = *(const float4*)p;
            wv[buf][2 * m + 1] = *(const float4*)(p + 4);
        }
    };
    auto loadW5 = [&](int buf, int t) {
#pragma unroll
        for (int m = 0; m < 4; ++m) {
            const float* p = W5b + (size_t)(wave * 64 + m * 16 + l16) * 256 + t * 32 + lk * 8;
            wv[buf][2 * m]     = *(const float4*)p;
            wv[buf][2 * m + 1] = *(const float4*)(p + 4);
        }
    };
    auto convW = [&](int buf) {
#pragma unroll
        for (int m = 0; m < 4; ++m) {
            const float f[8] = { wv[buf][2 * m].x,     wv[buf][2 * m].y,
                                 wv[buf][2 * m].z,     wv[buf][2 * m].w,
                                 wv[buf][2 * m + 1].x, wv[buf][2 * m + 1].y,
                                 wv[buf][2 * m + 1].z, wv[buf][2 * m + 1].w };
            union { bf16x8 v; u16 u[8]; } H, L;
#pragma unroll
            for (int e = 0; e < 8; ++e) {
                const u16 hh = bf16_rn(f[e]);
                H.u[e] = hh;
                L.u[e] = bf16_rn(f[e] - bf16_to_f(hh));
            }
            wh[m] = H.v;
            wl[m] = L.v;
        }
    };

    // ---- stage 1: no LDS, no barriers ----
    loadY(0, 0); loadW4(0, 0); loadY(1, 32); loadW4(1, 32);
#pragma unroll
    for (int it = 0; it < 8; ++it) {
        const int cur = it & 1;
        convW(cur);
        // prefetch issued BEFORE the MFMA cluster (wv[cur] is free now);
        // stage-1 tail pre-issues W5 chunks 0/1 for stage-2.
        if (it + 2 < 8) loadW4(cur, 32 * it + 64);
        else            loadW5(cur, it - 6);
        __builtin_amdgcn_s_setprio(1);
#pragma unroll
        for (int n = 0; n < 4; ++n) {
            union { bf16x8 v; u16 u[8]; } BH, BL;
#pragma unroll
            for (int j = 0; j < 8; ++j) {
                const u32 y = yf[cur][n][j];
                BH.u[j] = (u16)y;
                BL.u[j] = (u16)(y >> 16);
            }
#pragma unroll
            for (int m = 0; m < 4; ++m)
                acc1[m][n] = __builtin_amdgcn_mfma_f32_16x16x32_bf16(wh[m], BH.v, acc1[m][n], 0, 0, 0);
#pragma unroll
            for (int m = 0; m < 4; ++m)
                acc1[m][n] = __builtin_amdgcn_mfma_f32_16x16x32_bf16(wh[m], BL.v, acc1[m][n], 0, 0, 0);
#pragma unroll
            for (int m = 0; m < 4; ++m)
                acc1[m][n] = __builtin_amdgcn_mfma_f32_16x16x32_bf16(wl[m], BH.v, acc1[m][n], 0, 0, 0);
        }
        __builtin_amdgcn_s_setprio(0);
        if (it + 2 < 8) loadY(cur, 32 * it + 64);   // yf[cur] free after the n-loop
    }

    // ---- stage 2: double-buffered K-windows (window kw = acc1[kw]) ----
    f32x4 acc2[4][4];
#pragma unroll
    for (int m = 0; m < 4; ++m)
#pragma unroll
        for (int n = 0; n < 4; ++n)
            acc2[m][n] = (f32x4){0.f, 0.f, 0.f, 0.f};

    float b4v[4][4];
#pragma unroll
    for (int kw = 0; kw < 4; ++kw)
#pragma unroll
        for (int r = 0; r < 4; ++r)
            b4v[kw][r] = b4[(size_t)parent * 256 + ocbase + kw * 16 + lk * 4 + r];

    // write window kw into win buffer wb: k_global = i*4 + par, i = stage-1 row
    auto writeWin = [&](int kw, int wb) {
#pragma unroll
        for (int n = 0; n < 4; ++n) {
            const int colg = wave * 64 + n * 16 + l16;
            const int b_ = colg >> 2, par = colg & 3;
#pragma unroll
            for (int r = 0; r < 4; ++r) {
                const float v = fmaxf(acc1[kw][n][r] + b4v[kw][r], 0.f);
                const int k_ = lk * 16 + r * 4 + par;
                const u16 hh = bf16_rn(v);
                Whi_w[wb][b_ * LDW + k_] = hh;
                Wlo_w[wb][b_ * LDW + k_] = bf16_rn(v - bf16_to_f(hh));
            }
        }
    };

    writeWin(0, 0);                         // prologue (no barrier needed yet)

#pragma unroll
    for (int kw = 0; kw < 4; ++kw) {
        const int wb = kw & 1;
        bar_lds();                          // win[wb] visible; win[wb^1] reads done
        if (kw + 1 < 4) writeWin(kw + 1, wb ^ 1);
#pragma unroll
        for (int kc = 0; kc < 2; ++kc) {
            const int t = kw * 2 + kc;
            const int cur = t & 1;
            convW(cur);                     // waits on W5 chunk t (issued 2 ago)
            if (t + 2 < 8) loadW5(cur, t + 2);   // BEFORE the MFMA cluster
            __builtin_amdgcn_s_setprio(1);
#pragma unroll
            for (int n = 0; n < 4; ++n) {
                const int b_ = n * 16 + l16;
                const bf16x8 bhi = *(const bf16x8*)&Whi_w[wb][b_ * LDW + kc * 32 + 8 * lk];
                const bf16x8 blo = *(const bf16x8*)&Wlo_w[wb][b_ * LDW + kc * 32 + 8 * lk];
#pragma unroll
                for (int m = 0; m < 4; ++m)
                    acc2[m][n] = __builtin_amdgcn_mfma_f32_16x16x32_bf16(wh[m], bhi, acc2[m][n], 0, 0, 0);
#pragma unroll
                for (int m = 0; m < 4; ++m)
                    acc2[m][n] = __builtin_amdgcn_mfma_f32_16x16x32_bf16(wh[m], blo, acc2[m][n], 0, 0, 0);
#pragma unroll
                for (int m = 0; m < 4; ++m)
                    acc2[m][n] = __builtin_amdgcn_mfma_f32_16x16x32_bf16(wl[m], bhi, acc2[m][n], 0, 0, 0);
            }
            __builtin_amdgcn_s_setprio(0);
        }
    }

    // ---- fused final: per-wave child block, within-wave reduce over channels ----
    const int fy = 2 * cy + (wave >> 1), fx = 2 * cx + (wave & 1);
    const int blk = fy * 64 + fx;
    float wf0v[4][4], wf2v[4][4], biv[4][4];
#pragma unroll
    for (int m = 0; m < 4; ++m)
#pragma unroll
        for (int r = 0; r < 4; ++r) {
            const int cch = m * 16 + lk * 4 + r;
            wf0v[m][r] = wf[(size_t)blk * 256 + cch];
            wf2v[m][r] = wf[(size_t)blk * 256 + 128 + cch];
            biv[m][r]  = b5[(size_t)bid5 * 256 + wave * 64 + cch];
        }
    const float bf0 = bff[blk * 4 + 0], bf2 = bff[blk * 4 + 2];
#pragma unroll
    for (int n = 0; n < 4; ++n) {
        float a0 = 0.f, a2 = 0.f;
#pragma unroll
        for (int m = 0; m < 4; ++m)
#pragma unroll
            for (int r = 0; r < 4; ++r) {
                const float y = fmaxf(acc2[m][n][r] + biv[m][r], 0.f);
                a0 = fmaf(y, wf0v[m][r], a0);
                a2 = fmaf(y, wf2v[m][r], a2);
            }
        a0 += __shfl_xor(a0, 16); a0 += __shfl_xor(a0, 32);
        a2 += __shfl_xor(a2, 16); a2 += __shfl_xor(a2, 32);
        if (lk == n) {
            const float o0 = fmaxf(a0 + bf0, 0.f);
            const float o2 = fmaxf(a2 + bf2, 0.f);
            out[(size_t)(n * 16 + l16) * 4096 + blk] = (o0 - o2) * (1.0f / 4096.0f);
        }
    }
}

extern "C" void kernel_launch(void* const* d_in, const int* in_sizes, int n_in,
                              void* d_out, int out_size, void* d_ws, size_t ws_size,
                              hipStream_t stream) {
    (void)in_sizes; (void)n_in; (void)out_size; (void)ws_size;

    const float* xr = (const float*)d_in[0];
    const float* xi = (const float*)d_in[1];
    const float* w0 = (const float*)d_in[2];
    const float* b0 = (const float*)d_in[3];
    const float* wrec[5] = { (const float*)d_in[4],  (const float*)d_in[6],
                             (const float*)d_in[8],  (const float*)d_in[10],
                             (const float*)d_in[12] };
    const float* brec[5] = { (const float*)d_in[5],  (const float*)d_in[7],
                             (const float*)d_in[9],  (const float*)d_in[11],
                             (const float*)d_in[13] };
    const float* wf = (const float*)d_in[14];
    const float* bf = (const float*)d_in[15];
    float* out = (float*)d_out;

    u32* bufA = (u32*)d_ws;
    u32* bufB = bufA + (size_t)PLANE;
    u16* wc1  = (u16*)(bufB + (size_t)PLANE);
    u16* wc2  = wc1 + (size_t)2 * 262144;
    u16* wc3  = wc2 + (size_t)2 * 1048576;

    wconv_all_kernel<<<2688, 256, 0, stream>>>(wrec[0], wrec[1], wrec[2], wc1, wc2, wc3);

    layer0_kernel<<<dim3(256, 2), 256, 0, stream>>>(xr, xi, w0, b0, bufA);

    // layer 1: G=2,  S2=16, Nb=16384
    rec_mfma_kernel<128><<<dim3(128, 1, 4), 256, 0, stream>>>(
        bufA, wc1, wc1 + 262144, brec[0], bufB, 1, 4);
    // layer 2: G=4,  S2=8,  Nb=4096
    rec_mfma_kernel<128><<<dim3(32, 1, 16), 256, 0, stream>>>(
        bufB, wc2, wc2 + 1048576, brec[1], bufA, 2, 3);
    // layer 3: G=8,  S2=4,  Nb=1024
    rec_mfma_kernel<128><<<dim3(8, 1, 64), 256, 0, stream>>>(
        bufA, wc3, wc3 + 4194304, brec[2], bufB, 3, 2);
    // layers 4+5+final fused: one wg per L5 block
    rec45_final_kernel<<<1024, 256, 0, stream>>>(
        bufB, wrec[3], brec[3], wrec[4], brec[4], wf, bf, out);
}

// Round 9
// 281.673 us; speedup vs baseline: 1.0189x; 1.0189x over previous
//
#include <hip/hip_runtime.h>
#include <cstddef>

// ButterFlyNet2D IDFT forward. Split-bf16 MFMA (3-pass: Whi*Yhi + Whi*Ylo + Wlo*Yhi).
// Activations: ONE u32 per element = packed (hi bf16 | lo bf16<<16).
//   Plane layout A[gy][gx][i][k][l][b][p][q] -> per block contiguous Y[256][Nb].
// R9 (unbundled from R8 regression): rec kernels and stage-2 windows reverted
// to the R7 structure. Only kept changes vs R7:
//   (1) W5 prefetch issued BEFORE the stage-2 MFMA cluster + chunks 0/1
//       pre-issued from stage-1's tail (268 MB stream latency hiding);
//   (2) wconv and layer0 merged into ONE launch (they serialized for no reason).

typedef unsigned int  u32;
typedef unsigned short u16;
typedef __attribute__((ext_vector_type(8))) short bf16x8;
typedef __attribute__((ext_vector_type(4))) float f32x4;

#define PLANE 16777216   // elements per activation buffer

__device__ inline u16 bf16_rn(float x) {
    u32 u = __builtin_bit_cast(u32, x);
    u32 r = (u + 0x7FFFu + ((u >> 16) & 1u)) >> 16;
    return (u16)r;
}
__device__ inline float bf16_to_f(u16 h) {
    u32 u = ((u32)h) << 16;
    return __builtin_bit_cast(float, u);
}
__device__ inline u32 pack_split(float v) {
    const u16 h = bf16_rn(v);
    const u16 l = bf16_rn(v - bf16_to_f(h));
    return (u32)h | ((u32)l << 16);
}
// LDS-only barrier: drains ds ops, leaves global loads (vmcnt) in flight.
__device__ inline void bar_lds() {
    asm volatile("s_waitcnt lgkmcnt(0)\n\ts_barrier" ::: "memory");
}

// -------- merged: weight pre-convert (L1-3) + layer 0, one launch --------
// blocks [0, 2688): wconv of w1/w2/w3 (688128 8-elem groups)
// blocks [2688, 3200): layer0 (512 = 2 o-groups x 256 pixel-tiles)
__global__ __launch_bounds__(256)
void prep_kernel(const float* __restrict__ s1, const float* __restrict__ s2,
                 const float* __restrict__ s3,
                 u16* __restrict__ d1, u16* __restrict__ d2, u16* __restrict__ d3,
                 const float* __restrict__ xr, const float* __restrict__ xi,
                 const float* __restrict__ w0, const float* __restrict__ b0,
                 u32* __restrict__ A1) {
    const int bx  = blockIdx.x;
    const int tid = threadIdx.x;
    if (bx < 2688) {
        // ---- wconv path ----
        const int i = bx * 256 + tid;
        const float* s; u16 *dh, *dl; int off;
        if (i < 32768)        { s = s1; dh = d1; dl = d1 + 262144;  off = i; }
        else if (i < 163840)  { s = s2; dh = d2; dl = d2 + 1048576; off = i - 32768; }
        else                  { s = s3; dh = d3; dl = d3 + 4194304; off = i - 163840; }
        const float4 a = *(const float4*)(s + 8 * off);
        const float4 b = *(const float4*)(s + 8 * off + 4);
        union { bf16x8 v; u16 u[8]; } H, L;
        const float f[8] = {a.x, a.y, a.z, a.w, b.x, b.y, b.z, b.w};
#pragma unroll
        for (int e = 0; e < 8; ++e) {
            const u16 h = bf16_rn(f[e]);
            H.u[e] = h;
            L.u[e] = bf16_rn(f[e] - bf16_to_f(h));
        }
        *(bf16x8*)(dh + 8 * off) = H.v;
        *(bf16x8*)(dl + 8 * off) = L.v;
        return;
    }
    // ---- layer0 path ----
    __shared__ float w0s[128][16];
    __shared__ float b0s[128];
    const int lb = bx - 2688;
    const int og = lb >> 8;                 // 0/1: o = og*128 + j
    {
        const int row = tid >> 1, half = tid & 1;
        const float4 wa = *(const float4*)(w0 + (og * 128 + row) * 16 + half * 8);
        const float4 wb = *(const float4*)(w0 + (og * 128 + row) * 16 + half * 8 + 4);
        *(float4*)&w0s[row][half * 8]     = wa;
        *(float4*)&w0s[row][half * 8 + 4] = wb;
        if (tid < 128) b0s[tid] = b0[og * 128 + tid];
    }
    __syncthreads();

    const int n = (lb & 255) * 256 + tid;   // output pixel: b*1024 + p*32 + q
    const int b = n >> 10, p = (n >> 5) & 31, q = n & 31;
    float xs[16];
#pragma unroll
    for (int k = 0; k < 2; ++k) {
        const float2 vr = *(const float2*)(xr + b * 4096 + (2 * p + k) * 64 + 2 * q);
        const float2 vi = *(const float2*)(xi + b * 4096 + (2 * p + k) * 64 + 2 * q);
        xs[0  + k * 2 + 0] = fmaxf(vr.x, 0.f);  xs[0  + k * 2 + 1] = fmaxf(vr.y, 0.f);
        xs[4  + k * 2 + 0] = fmaxf(vi.x, 0.f);  xs[4  + k * 2 + 1] = fmaxf(vi.y, 0.f);
        xs[8  + k * 2 + 0] = fmaxf(-vr.x, 0.f); xs[8  + k * 2 + 1] = fmaxf(-vr.y, 0.f);
        xs[12 + k * 2 + 0] = fmaxf(-vi.x, 0.f); xs[12 + k * 2 + 1] = fmaxf(-vi.y, 0.f);
    }
    const int kp = p & 1, lp = q & 1, pp = p >> 1, qp = q >> 1;
    const size_t pixoff = (size_t)(b * 256 + pp * 16 + qp);
#pragma unroll
    for (int j = 0; j < 128; ++j) {
        float acc = b0s[j];
#pragma unroll
        for (int e = 0; e < 16; ++e) acc = fmaf(xs[e], w0s[j][e], acc);
        acc = fmaxf(acc, 0.f);
        const int o = og * 128 + j;
        const int gy = o >> 7, gx = (o >> 6) & 1, c = o & 63;
        const size_t flat = (size_t)((((gy * 2 + gx) * 64 + c) * 2 + kp) * 2 + lp) * (64 * 256)
                          + pixoff;
        A1[flat] = pack_split(acc);
    }
}

// ---------------- Recursion layers 1..3 : split-bf16 MFMA, W direct ----------------
// (R7 structure: single LDS buffer, two lgkm-only barriers per K-step.)
template<int NT>
__global__ __launch_bounds__(256, 2)
void rec_mfma_kernel(const u32* __restrict__ Yg,
                     const u16* __restrict__ Whi_g, const u16* __restrict__ Wlo_g,
                     const float* __restrict__ bias, u32* __restrict__ Aout,
                     const int lgG, const int lgS2) {
    constexpr int NF  = NT / 16;
    constexpr int LD  = 40;
    constexpr int NCP = NT / 2;
    constexpr int RPT = 32 / (256 / NCP);

    __shared__ u16 Yhi_s[NT * LD];
    __shared__ u16 Ylo_s[NT * LD];

    const int G  = 1 << lgG;
    const int S2 = 1 << lgS2;
    const int Nb = 64 << (2 * lgS2);

    // XCD-chunked swizzle: keep all n-tiles of a block on one XCD (W L2 reuse)
    int bid, nt;
    const int nBid = G * G, NTILES = gridDim.x;
    if (nBid >= 8) {
        const int h = blockIdx.z * NTILES + blockIdx.x;
        const int xcd = h & 7, j = h >> 3, per = nBid >> 3;
        bid = xcd * per + j / NTILES;
        nt  = j % NTILES;
    } else { bid = blockIdx.z; nt = blockIdx.x; }

    const size_t wbase = (size_t)bid * 65536;
    const u32* Yblk = Yg + (size_t)bid * 256 * (size_t)Nb + (size_t)nt * NT;

    const int tid = threadIdx.x, wave = tid >> 6, lane = tid & 63;
    const int l16 = lane & 15, lk = lane >> 4;
    const int cp = tid % NCP, rg = tid / NCP;
    const int col0 = cp * 2, trow = rg * RPT;

    f32x4 acc[4][NF];
#pragma unroll
    for (int m = 0; m < 4; ++m)
#pragma unroll
        for (int n = 0; n < NF; ++n)
            acc[m][n] = (f32x4){0.f, 0.f, 0.f, 0.f};

    uint2  yreg[2][RPT];
    bf16x8 wh[4], wl[4];
    u32 yhw[2][RPT / 2], ylw[2][RPT / 2];

    auto loadY = [&](int ybuf, int k0) {
#pragma unroll
        for (int r = 0; r < RPT; ++r)
            yreg[ybuf][r] = *(const uint2*)(Yblk + (size_t)(k0 + trow + r) * Nb + col0);
    };
    auto loadWpre = [&](int k0) {
#pragma unroll
        for (int m = 0; m < 4; ++m) {
            const size_t off = wbase + (size_t)(wave * 64 + m * 16 + l16) * 256 + k0 + lk * 8;
            wh[m] = *(const bf16x8*)(Whi_g + off);
            wl[m] = *(const bf16x8*)(Wlo_g + off);
        }
    };
    auto prepY = [&](int ybuf) {
#pragma unroll
        for (int c = 0; c < 2; ++c)
#pragma unroll
            for (int j2 = 0; j2 < RPT / 2; ++j2) {
                const u32 a = c ? yreg[ybuf][2 * j2].y     : yreg[ybuf][2 * j2].x;
                const u32 b = c ? yreg[ybuf][2 * j2 + 1].y : yreg[ybuf][2 * j2 + 1].x;
                yhw[c][j2] = (a & 0xFFFFu) | (b << 16);
                ylw[c][j2] = (a >> 16)     | (b & 0xFFFF0000u);
            }
    };
    auto stageY = [&]() {
#pragma unroll
        for (int c = 0; c < 2; ++c) {
            if constexpr (RPT == 8) {
                *(uint4*)&Yhi_s[(col0 + c) * LD + trow] = make_uint4(yhw[c][0], yhw[c][1], yhw[c][2], yhw[c][3]);
                *(uint4*)&Ylo_s[(col0 + c) * LD + trow] = make_uint4(ylw[c][0], ylw[c][1], ylw[c][2], ylw[c][3]);
            } else {
                *(uint2*)&Yhi_s[(col0 + c) * LD + trow] = make_uint2(yhw[c][0], yhw[c][1]);
                *(uint2*)&Ylo_s[(col0 + c) * LD + trow] = make_uint2(ylw[c][0], ylw[c][1]);
            }
        }
    };

    loadY(0, 0); loadY(1, 32);

#pragma unroll
    for (int it = 0; it < 8; ++it) {
        const int k0 = it * 32;
        const int cur = it & 1;
        loadWpre(k0);            // in flight across barriers (no vmcnt drain)
        prepY(cur);              // waits on yreg[cur] (issued 2 iters ago)
        bar_lds();               // prev MFMA ds_reads done; LDS reusable
        stageY();
        bar_lds();               // Y tile visible
        if (it + 2 < 8) loadY(cur, k0 + 64);
        __builtin_amdgcn_s_setprio(1);
#pragma unroll
        for (int n = 0; n < NF; ++n) {
            const int ccol = n * 16 + l16;
            const bf16x8 bhi = *(const bf16x8*)&Yhi_s[ccol * LD + 8 * lk];
            const bf16x8 blo = *(const bf16x8*)&Ylo_s[ccol * LD + 8 * lk];
#pragma unroll
            for (int m = 0; m < 4; ++m)
                acc[m][n] = __builtin_amdgcn_mfma_f32_16x16x32_bf16(wh[m], bhi, acc[m][n], 0, 0, 0);
#pragma unroll
            for (int m = 0; m < 4; ++m)
                acc[m][n] = __builtin_amdgcn_mfma_f32_16x16x32_bf16(wh[m], blo, acc[m][n], 0, 0, 0);
#pragma unroll
            for (int m = 0; m < 4; ++m)
                acc[m][n] = __builtin_amdgcn_mfma_f32_16x16x32_bf16(wl[m], bhi, acc[m][n], 0, 0, 0);
        }
        __builtin_amdgcn_s_setprio(0);
    }

    // ---- epilogue: bias + relu + packed scatter to child blocks ----
    const int gy = bid >> lgG, gx = bid & (G - 1);
    const int NS2 = S2 >> 1;
#pragma unroll
    for (int m = 0; m < 4; ++m) {
#pragma unroll
        for (int r = 0; r < 4; ++r) {
            const int oc = wave * 64 + m * 16 + lk * 4 + r;   // C/D: row=(lane>>4)*4+reg
            const float bi = bias[(size_t)bid * 256 + oc];
            const int yl = oc >> 7, xl = (oc >> 6) & 1, cch = oc & 63;
            const int cy = 2 * gy + yl, cx = 2 * gx + xl;
            const size_t base = (size_t)((cy * (2 * G) + cx) * 64 + cch);
#pragma unroll
            for (int n = 0; n < NF; ++n) {
                const float v = fmaxf(acc[m][n][r] + bi, 0.f);
                const int ng = nt * NT + n * 16 + l16;        // C/D: col=lane&15
                const int b   = ng >> (2 * lgS2);
                const int rem = ng & ((1 << (2 * lgS2)) - 1);
                const int p = rem >> lgS2, q = rem & (S2 - 1);
                const size_t flat = ((base * 2 + (p & 1)) * 2 + (q & 1)) * (size_t)(64 * NS2 * NS2)
                                  + (size_t)(b * NS2 * NS2 + (p >> 1) * NS2 + (q >> 1));
                Aout[flat] = pack_split(v);
            }
        }
    }
}

// ---------------- Fused L4 + L5 + final ----------------
// R7 structure; only change: W5 prefetch issued BEFORE the MFMA cluster and
// chunks 0/1 pre-issued from stage-1's tail.
__global__ __launch_bounds__(256, 2)
void rec45_final_kernel(const u32* __restrict__ Yg, const float* __restrict__ W4,
                        const float* __restrict__ b4, const float* __restrict__ W5,
                        const float* __restrict__ b5, const float* __restrict__ wf,
                        const float* __restrict__ bff, float* __restrict__ out) {
    constexpr int LDW = 72;                 // window row stride (u16)
    __shared__ u16 Whi_w[64 * LDW];
    __shared__ u16 Wlo_w[64 * LDW];

    const int h = blockIdx.x;
    const int parent = ((h >> 5) << 3) | (h & 7);   // 0..255 = pgy*16+pgx
    const int child  = (h >> 3) & 3;
    const int pgy = parent >> 4, pgx = parent & 15;
    const int cy = 2 * pgy + (child >> 1), cx = 2 * pgx + (child & 1);
    const int bid5 = cy * 32 + cx;
    const int ocbase = child * 64;

    const u32* Yblk  = Yg + (size_t)parent * 65536;
    const float* W4s = W4 + (size_t)parent * 65536 + (size_t)ocbase * 256;
    const float* W5b = W5 + (size_t)bid5 * 65536;

    const int tid = threadIdx.x, wave = tid >> 6, lane = tid & 63;
    const int l16 = lane & 15, lk = lane >> 4;

    f32x4 acc1[4][4];
#pragma unroll
    for (int m = 0; m < 4; ++m)
#pragma unroll
        for (int n = 0; n < 4; ++n)
            acc1[m][n] = (f32x4){0.f, 0.f, 0.f, 0.f};

    u32    yf[2][4][8];
    float4 wv[2][8];
    bf16x8 wh[4], wl[4];

    auto loadY = [&](int buf, int k0) {
#pragma unroll
        for (int n = 0; n < 4; ++n)
#pragma unroll
            for (int j = 0; j < 8; ++j)
                yf[buf][n][j] = Yblk[(size_t)(k0 + 8 * lk + j) * 256 + wave * 64 + n * 16 + l16];
    };
    auto loadW4 = [&](int buf, int k0) {
#pragma unroll
        for (int m = 0; m < 4; ++m) {
            const float* p = W4s + (size_t)(m * 16 + l16) * 256 + k0 + lk * 8;
            wv[buf][2 * m]     = *(const float4*)p;
            wv[buf][2 * m + 1] = *(const float4*)(p + 4);
        }
    };
    auto loadW5 = [&](int buf, int t) {
#pragma unroll
        for (int m = 0; m < 4; ++m) {
            const float* p = W5b + (size_t)(wave * 64 + m * 16 + l16) * 256 + t * 32 + lk * 8;
            wv[buf][2 * m]     = *(const float4*)p;
            wv[buf][2 * m + 1] = *(const float4*)(p + 4);
        }
    };
    auto convW = [&](int buf) {
#pragma unroll
        for (int m = 0; m < 4; ++m) {
            const float f[8] = { wv[buf][2 * m].x,     wv[buf][2 * m].y,
                                 wv[buf][2 * m].z,     wv[buf][2 * m].w,
                                 wv[buf][2 * m + 1].x, wv[buf][2 * m + 1].y,
                                 wv[buf][2 * m + 1].z, wv[buf][2 * m + 1].w };
            union { bf16x8 v; u16 u[8]; } H, L;
#pragma unroll
            for (int e = 0; e < 8; ++e) {
                const u16 hh = bf16_rn(f[e]);
                H.u[e] = hh;
                L.u[e] = bf16_rn(f[e] - bf16_to_f(hh));
            }
            wh[m] = H.v;
            wl[m] = L.v;
        }
    };

    // ---- stage 1: no LDS, no barriers (R7 placement) ----
    loadY(0, 0); loadW4(0, 0); loadY(1, 32); loadW4(1, 32);
#pragma unroll
    for (int it = 0; it < 8; ++it) {
        const int cur = it & 1;
        convW(cur);
        if (it >= 6) loadW5(cur, it - 6);    // pre-issue W5 chunks 0/1 (wv[cur] free)
        __builtin_amdgcn_s_setprio(1);
#pragma unroll
        for (int n = 0; n < 4; ++n) {
            union { bf16x8 v; u16 u[8]; } BH, BL;
#pragma unroll
            for (int j = 0; j < 8; ++j) {
                const u32 y = yf[cur][n][j];
                BH.u[j] = (u16)y;
                BL.u[j] = (u16)(y >> 16);
            }
#pragma unroll
            for (int m = 0; m < 4; ++m)
                acc1[m][n] = __builtin_amdgcn_mfma_f32_16x16x32_bf16(wh[m], BH.v, acc1[m][n], 0, 0, 0);
#pragma unroll
            for (int m = 0; m < 4; ++m)
                acc1[m][n] = __builtin_amdgcn_mfma_f32_16x16x32_bf16(wh[m], BL.v, acc1[m][n], 0, 0, 0);
#pragma unroll
            for (int m = 0; m < 4; ++m)
                acc1[m][n] = __builtin_amdgcn_mfma_f32_16x16x32_bf16(wl[m], BH.v, acc1[m][n], 0, 0, 0);
        }
        __builtin_amdgcn_s_setprio(0);
        if (it + 2 < 8) { loadY(cur, 32 * it + 64); loadW4(cur, 32 * it + 64); }
    }

    // ---- stage 2: K-windows of 64 (window kw = acc1[kw]), R7 single-buffer ----
    f32x4 acc2[4][4];
#pragma unroll
    for (int m = 0; m < 4; ++m)
#pragma unroll
        for (int n = 0; n < 4; ++n)
            acc2[m][n] = (f32x4){0.f, 0.f, 0.f, 0.f};

    float b4v[4][4];
#pragma unroll
    for (int kw = 0; kw < 4; ++kw)
#pragma unroll
        for (int r = 0; r < 4; ++r)
            b4v[kw][r] = b4[(size_t)parent * 256 + ocbase + kw * 16 + lk * 4 + r];

#pragma unroll
    for (int kw = 0; kw < 4; ++kw) {
        // write window kw: k_global = i*4 + par, i = kw*16 + lk*4 + r
#pragma unroll
        for (int n = 0; n < 4; ++n) {
            const int colg = wave * 64 + n * 16 + l16;
            const int b_ = colg >> 2, par = colg & 3;
#pragma unroll
            for (int r = 0; r < 4; ++r) {
                const float v = fmaxf(acc1[kw][n][r] + b4v[kw][r], 0.f);
                const int k_ = lk * 16 + r * 4 + par;
                const u16 hh = bf16_rn(v);
                Whi_w[b_ * LDW + k_] = hh;
                Wlo_w[b_ * LDW + k_] = bf16_rn(v - bf16_to_f(hh));
            }
        }
        bar_lds();                       // window visible (global loads in flight)
#pragma unroll
        for (int kc = 0; kc < 2; ++kc) {
            const int t = kw * 2 + kc;
            const int cur = t & 1;
            convW(cur);                  // waits on W5 chunk t (issued 2 ago)
            if (t + 2 < 8) loadW5(cur, t + 2);   // BEFORE the MFMA cluster
            __builtin_amdgcn_s_setprio(1);
#pragma unroll
            for (int n = 0; n < 4; ++n) {
                const int b_ = n * 16 + l16;
                const bf16x8 bhi = *(const bf16x8*)&Whi_w[b_ * LDW + kc * 32 + 8 * lk];
                const bf16x8 blo = *(const bf16x8*)&Wlo_w[b_ * LDW + kc * 32 + 8 * lk];
#pragma unroll
                for (int m = 0; m < 4; ++m)
                    acc2[m][n] = __builtin_amdgcn_mfma_f32_16x16x32_bf16(wh[m], bhi, acc2[m][n], 0, 0, 0);
#pragma unroll
                for (int m = 0; m < 4; ++m)
                    acc2[m][n] = __builtin_amdgcn_mfma_f32_16x16x32_bf16(wh[m], blo, acc2[m][n], 0, 0, 0);
#pragma unroll
                for (int m = 0; m < 4; ++m)
                    acc2[m][n] = __builtin_amdgcn_mfma_f32_16x16x32_bf16(wl[m], bhi, acc2[m][n], 0, 0, 0);
            }
            __builtin_amdgcn_s_setprio(0);
        }
        bar_lds();                       // reads of window kw done before next write
    }

    // ---- fused final: per-wave child block, within-wave reduce over channels ----
    const int fy = 2 * cy + (wave >> 1), fx = 2 * cx + (wave & 1);
    const int blk = fy * 64 + fx;
    float wf0v[4][4], wf2v[4][4], biv[4][4];
#pragma unroll
    for (int m = 0; m < 4; ++m)
#pragma unroll
        for (int r = 0; r < 4; ++r) {
            const int cch = m * 16 + lk * 4 + r;
            wf0v[m][r] = wf[(size_t)blk * 256 + cch];
            wf2v[m][r] = wf[(size_t)blk * 256 + 128 + cch];
            biv[m][r]  = b5[(size_t)bid5 * 256 + wave * 64 + cch];
        }
    const float bf0 = bff[blk * 4 + 0], bf2 = bff[blk * 4 + 2];
#pragma unroll
    for (int n = 0; n < 4; ++n) {
        float a0 = 0.f, a2 = 0.f;
#pragma unroll
        for (int m = 0; m < 4; ++m)
#pragma unroll
            for (int r = 0; r < 4; ++r) {
                const float y = fmaxf(acc2[m][n][r] + biv[m][r], 0.f);
                a0 = fmaf(y, wf0v[m][r], a0);
                a2 = fmaf(y, wf2v[m][r], a2);
            }
        a0 += __shfl_xor(a0, 16); a0 += __shfl_xor(a0, 32);
        a2 += __shfl_xor(a2, 16); a2 += __shfl_xor(a2, 32);
        if (lk == n) {
            const float o0 = fmaxf(a0 + bf0, 0.f);
            const float o2 = fmaxf(a2 + bf2, 0.f);
            out[(size_t)(n * 16 + l16) * 4096 + blk] = (o0 - o2) * (1.0f / 4096.0f);
        }
    }
}

extern "C" void kernel_launch(void* const* d_in, const int* in_sizes, int n_in,
                              void* d_out, int out_size, void* d_ws, size_t ws_size,
                              hipStream_t stream) {
    (void)in_sizes; (void)n_in; (void)out_size; (void)ws_size;

    const float* xr = (const float*)d_in[0];
    const float* xi = (const float*)d_in[1];
    const float* w0 = (const float*)d_in[2];
    const float* b0 = (const float*)d_in[3];
    const float* wrec[5] = { (const float*)d_in[4],  (const float*)d_in[6],
                             (const float*)d_in[8],  (const float*)d_in[10],
                             (const float*)d_in[12] };
    const float* brec[5] = { (const float*)d_in[5],  (const float*)d_in[7],
                             (const float*)d_in[9],  (const float*)d_in[11],
                             (const float*)d_in[13] };
    const float* wf = (const float*)d_in[14];
    const float* bf = (const float*)d_in[15];
    float* out = (float*)d_out;

    u32* bufA = (u32*)d_ws;
    u32* bufB = bufA + (size_t)PLANE;
    u16* wc1  = (u16*)(bufB + (size_t)PLANE);
    u16* wc2  = wc1 + (size_t)2 * 262144;
    u16* wc3  = wc2 + (size_t)2 * 1048576;

    // wconv (2688 wg) + layer0 (512 wg) in one launch
    prep_kernel<<<3200, 256, 0, stream>>>(wrec[0], wrec[1], wrec[2], wc1, wc2, wc3,
                                          xr, xi, w0, b0, bufA);

    // layer 1: G=2,  S2=16, Nb=16384
    rec_mfma_kernel<128><<<dim3(128, 1, 4), 256, 0, stream>>>(
        bufA, wc1, wc1 + 262144, brec[0], bufB, 1, 4);
    // layer 2: G=4,  S2=8,  Nb=4096
    rec_mfma_kernel<128><<<dim3(32, 1, 16), 256, 0, stream>>>(
        bufB, wc2, wc2 + 1048576, brec[1], bufA, 2, 3);
    // layer 3: G=8,  S2=4,  Nb=1024
    rec_mfma_kernel<128><<<dim3(8, 1, 64), 256, 0, stream>>>(
        bufA, wc3, wc3 + 4194304, brec[2], bufB, 3, 2);
    // layers 4+5+final fused: one wg per L5 block
    rec45_final_kernel<<<1024, 256, 0, stream>>>(
        bufB, wrec[3], brec[3], wrec[4], brec[4], wf, bf, out);
}

// Round 10
// 269.647 us; speedup vs baseline: 1.0643x; 1.0446x over previous
//
#include <hip/hip_runtime.h>
#include <cstddef>

// ButterFlyNet2D IDFT forward. Split-bf16 MFMA (3-pass: Whi*Yhi + Whi*Ylo + Wlo*Yhi).
// Activations: ONE u32 per element = packed (hi bf16 | lo bf16<<16).
//   Plane layout A[gy][gx][i][k][l][b][p][q] -> per block contiguous Y[256][Nb].
// R10 = exact R7 structure (270.6 us baseline) + ONE change: convW in the fused
// L4/L5 kernel uses truncation-split (hi = bit-trunc, lo = trunc of exact
// remainder) instead of RN-split: ~2x fewer VALU ops on the in-loop critical
// path; representation error 2^-17 -> 2^-16 (negligible vs summation noise).

typedef unsigned int  u32;
typedef unsigned short u16;
typedef __attribute__((ext_vector_type(8))) short bf16x8;
typedef __attribute__((ext_vector_type(4))) float f32x4;

#define PLANE 16777216   // elements per activation buffer

__device__ inline u16 bf16_rn(float x) {
    u32 u = __builtin_bit_cast(u32, x);
    u32 r = (u + 0x7FFFu + ((u >> 16) & 1u)) >> 16;
    return (u16)r;
}
__device__ inline float bf16_to_f(u16 h) {
    u32 u = ((u32)h) << 16;
    return __builtin_bit_cast(float, u);
}
__device__ inline u32 pack_split(float v) {
    const u16 h = bf16_rn(v);
    const u16 l = bf16_rn(v - bf16_to_f(h));
    return (u32)h | ((u32)l << 16);
}
// LDS-only barrier: drains ds ops, leaves global loads (vmcnt) in flight.
__device__ inline void bar_lds() {
    asm volatile("s_waitcnt lgkmcnt(0)\n\ts_barrier" ::: "memory");
}

// ---------------- weight pre-convert (layers 1-3, one launch) ----------------
__global__ __launch_bounds__(256)
void wconv_all_kernel(const float* __restrict__ s1, const float* __restrict__ s2,
                      const float* __restrict__ s3,
                      u16* __restrict__ d1, u16* __restrict__ d2, u16* __restrict__ d3) {
    const int i = blockIdx.x * 256 + threadIdx.x;   // 8-elem group, 688128 total
    const float* s; u16 *dh, *dl; int off;
    if (i < 32768)        { s = s1; dh = d1; dl = d1 + 262144;  off = i; }
    else if (i < 163840)  { s = s2; dh = d2; dl = d2 + 1048576; off = i - 32768; }
    else                  { s = s3; dh = d3; dl = d3 + 4194304; off = i - 163840; }
    const float4 a = *(const float4*)(s + 8 * off);
    const float4 b = *(const float4*)(s + 8 * off + 4);
    union { bf16x8 v; u16 u[8]; } H, L;
    const float f[8] = {a.x, a.y, a.z, a.w, b.x, b.y, b.z, b.w};
#pragma unroll
    for (int e = 0; e < 8; ++e) {
        const u16 h = bf16_rn(f[e]);
        H.u[e] = h;
        L.u[e] = bf16_rn(f[e] - bf16_to_f(h));
    }
    *(bf16x8*)(dh + 8 * off) = H.v;
    *(bf16x8*)(dl + 8 * off) = L.v;
}

// ---------------- Layer 0: x read once, 128 outputs per thread ----------------
__global__ __launch_bounds__(256)
void layer0_kernel(const float* __restrict__ xr, const float* __restrict__ xi,
                   const float* __restrict__ w0, const float* __restrict__ b0,
                   u32* __restrict__ A1) {
    __shared__ float w0s[128][16];
    __shared__ float b0s[128];
    const int og  = blockIdx.y;             // 0/1: o = og*128 + j
    const int tid = threadIdx.x;
    {
        const int row = tid >> 1, half = tid & 1;
        const float4 wa = *(const float4*)(w0 + (og * 128 + row) * 16 + half * 8);
        const float4 wb = *(const float4*)(w0 + (og * 128 + row) * 16 + half * 8 + 4);
        *(float4*)&w0s[row][half * 8]     = wa;
        *(float4*)&w0s[row][half * 8 + 4] = wb;
        if (tid < 128) b0s[tid] = b0[og * 128 + tid];
    }
    __syncthreads();

    const int n = blockIdx.x * 256 + tid;   // output pixel: b*1024 + p*32 + q
    const int b = n >> 10, p = (n >> 5) & 31, q = n & 31;
    float xs[16];
#pragma unroll
    for (int k = 0; k < 2; ++k) {
        const float2 vr = *(const float2*)(xr + b * 4096 + (2 * p + k) * 64 + 2 * q);
        const float2 vi = *(const float2*)(xi + b * 4096 + (2 * p + k) * 64 + 2 * q);
        xs[0  + k * 2 + 0] = fmaxf(vr.x, 0.f);  xs[0  + k * 2 + 1] = fmaxf(vr.y, 0.f);
        xs[4  + k * 2 + 0] = fmaxf(vi.x, 0.f);  xs[4  + k * 2 + 1] = fmaxf(vi.y, 0.f);
        xs[8  + k * 2 + 0] = fmaxf(-vr.x, 0.f); xs[8  + k * 2 + 1] = fmaxf(-vr.y, 0.f);
        xs[12 + k * 2 + 0] = fmaxf(-vi.x, 0.f); xs[12 + k * 2 + 1] = fmaxf(-vi.y, 0.f);
    }
    const int kp = p & 1, lp = q & 1, pp = p >> 1, qp = q >> 1;
    const size_t pixoff = (size_t)(b * 256 + pp * 16 + qp);
#pragma unroll
    for (int j = 0; j < 128; ++j) {
        float acc = b0s[j];
#pragma unroll
        for (int e = 0; e < 16; ++e) acc = fmaf(xs[e], w0s[j][e], acc);
        acc = fmaxf(acc, 0.f);
        const int o = og * 128 + j;
        const int gy = o >> 7, gx = (o >> 6) & 1, c = o & 63;
        const size_t flat = (size_t)((((gy * 2 + gx) * 64 + c) * 2 + kp) * 2 + lp) * (64 * 256)
                          + pixoff;
        A1[flat] = pack_split(acc);
    }
}

// ---------------- Recursion layers 1..3 : split-bf16 MFMA, W direct ----------------
template<int NT>
__global__ __launch_bounds__(256, 2)
void rec_mfma_kernel(const u32* __restrict__ Yg,
                     const u16* __restrict__ Whi_g, const u16* __restrict__ Wlo_g,
                     const float* __restrict__ bias, u32* __restrict__ Aout,
                     const int lgG, const int lgS2) {
    constexpr int NF  = NT / 16;
    constexpr int LD  = 40;
    constexpr int NCP = NT / 2;
    constexpr int RPT = 32 / (256 / NCP);

    __shared__ u16 Yhi_s[NT * LD];
    __shared__ u16 Ylo_s[NT * LD];

    const int G  = 1 << lgG;
    const int S2 = 1 << lgS2;
    const int Nb = 64 << (2 * lgS2);

    // XCD-chunked swizzle: keep all n-tiles of a block on one XCD (W L2 reuse)
    int bid, nt;
    const int nBid = G * G, NTILES = gridDim.x;
    if (nBid >= 8) {
        const int h = blockIdx.z * NTILES + blockIdx.x;
        const int xcd = h & 7, j = h >> 3, per = nBid >> 3;
        bid = xcd * per + j / NTILES;
        nt  = j % NTILES;
    } else { bid = blockIdx.z; nt = blockIdx.x; }

    const size_t wbase = (size_t)bid * 65536;
    const u32* Yblk = Yg + (size_t)bid * 256 * (size_t)Nb + (size_t)nt * NT;

    const int tid = threadIdx.x, wave = tid >> 6, lane = tid & 63;
    const int l16 = lane & 15, lk = lane >> 4;
    const int cp = tid % NCP, rg = tid / NCP;
    const int col0 = cp * 2, trow = rg * RPT;

    f32x4 acc[4][NF];
#pragma unroll
    for (int m = 0; m < 4; ++m)
#pragma unroll
        for (int n = 0; n < NF; ++n)
            acc[m][n] = (f32x4){0.f, 0.f, 0.f, 0.f};

    uint2  yreg[2][RPT];
    bf16x8 wh[4], wl[4];
    u32 yhw[2][RPT / 2], ylw[2][RPT / 2];

    auto loadY = [&](int ybuf, int k0) {
#pragma unroll
        for (int r = 0; r < RPT; ++r)
            yreg[ybuf][r] = *(const uint2*)(Yblk + (size_t)(k0 + trow + r) * Nb + col0);
    };
    auto loadWpre = [&](int k0) {
#pragma unroll
        for (int m = 0; m < 4; ++m) {
            const size_t off = wbase + (size_t)(wave * 64 + m * 16 + l16) * 256 + k0 + lk * 8;
            wh[m] = *(const bf16x8*)(Whi_g + off);
            wl[m] = *(const bf16x8*)(Wlo_g + off);
        }
    };
    auto prepY = [&](int ybuf) {
#pragma unroll
        for (int c = 0; c < 2; ++c)
#pragma unroll
            for (int j2 = 0; j2 < RPT / 2; ++j2) {
                const u32 a = c ? yreg[ybuf][2 * j2].y     : yreg[ybuf][2 * j2].x;
                const u32 b = c ? yreg[ybuf][2 * j2 + 1].y : yreg[ybuf][2 * j2 + 1].x;
                yhw[c][j2] = (a & 0xFFFFu) | (b << 16);
                ylw[c][j2] = (a >> 16)     | (b & 0xFFFF0000u);
            }
    };
    auto stageY = [&]() {
#pragma unroll
        for (int c = 0; c < 2; ++c) {
            if constexpr (RPT == 8) {
                *(uint4*)&Yhi_s[(col0 + c) * LD + trow] = make_uint4(yhw[c][0], yhw[c][1], yhw[c][2], yhw[c][3]);
                *(uint4*)&Ylo_s[(col0 + c) * LD + trow] = make_uint4(ylw[c][0], ylw[c][1], ylw[c][2], ylw[c][3]);
            } else {
                *(uint2*)&Yhi_s[(col0 + c) * LD + trow] = make_uint2(yhw[c][0], yhw[c][1]);
                *(uint2*)&Ylo_s[(col0 + c) * LD + trow] = make_uint2(ylw[c][0], ylw[c][1]);
            }
        }
    };

    loadY(0, 0); loadY(1, 32);

#pragma unroll
    for (int it = 0; it < 8; ++it) {
        const int k0 = it * 32;
        const int cur = it & 1;
        loadWpre(k0);            // in flight across barriers (no vmcnt drain)
        prepY(cur);              // waits on yreg[cur] (issued 2 iters ago)
        bar_lds();               // prev MFMA ds_reads done; LDS reusable
        stageY();
        bar_lds();               // Y tile visible
        if (it + 2 < 8) loadY(cur, k0 + 64);
        __builtin_amdgcn_s_setprio(1);
#pragma unroll
        for (int n = 0; n < NF; ++n) {
            const int ccol = n * 16 + l16;
            const bf16x8 bhi = *(const bf16x8*)&Yhi_s[ccol * LD + 8 * lk];
            const bf16x8 blo = *(const bf16x8*)&Ylo_s[ccol * LD + 8 * lk];
#pragma unroll
            for (int m = 0; m < 4; ++m)
                acc[m][n] = __builtin_amdgcn_mfma_f32_16x16x32_bf16(wh[m], bhi, acc[m][n], 0, 0, 0);
#pragma unroll
            for (int m = 0; m < 4; ++m)
                acc[m][n] = __builtin_amdgcn_mfma_f32_16x16x32_bf16(wh[m], blo, acc[m][n], 0, 0, 0);
#pragma unroll
            for (int m = 0; m < 4; ++m)
                acc[m][n] = __builtin_amdgcn_mfma_f32_16x16x32_bf16(wl[m], bhi, acc[m][n], 0, 0, 0);
        }
        __builtin_amdgcn_s_setprio(0);
    }

    // ---- epilogue: bias + relu + packed scatter to child blocks ----
    const int gy = bid >> lgG, gx = bid & (G - 1);
    const int NS2 = S2 >> 1;
#pragma unroll
    for (int m = 0; m < 4; ++m) {
#pragma unroll
        for (int r = 0; r < 4; ++r) {
            const int oc = wave * 64 + m * 16 + lk * 4 + r;   // C/D: row=(lane>>4)*4+reg
            const float bi = bias[(size_t)bid * 256 + oc];
            const int yl = oc >> 7, xl = (oc >> 6) & 1, cch = oc & 63;
            const int cy = 2 * gy + yl, cx = 2 * gx + xl;
            const size_t base = (size_t)((cy * (2 * G) + cx) * 64 + cch);
#pragma unroll
            for (int n = 0; n < NF; ++n) {
                const float v = fmaxf(acc[m][n][r] + bi, 0.f);
                const int ng = nt * NT + n * 16 + l16;        // C/D: col=lane&15
                const int b   = ng >> (2 * lgS2);
                const int rem = ng & ((1 << (2 * lgS2)) - 1);
                const int p = rem >> lgS2, q = rem & (S2 - 1);
                const size_t flat = ((base * 2 + (p & 1)) * 2 + (q & 1)) * (size_t)(64 * NS2 * NS2)
                                  + (size_t)(b * NS2 * NS2 + (p >> 1) * NS2 + (q >> 1));
                Aout[flat] = pack_split(v);
            }
        }
    }
}

// ---------------- Fused L4 + L5 + final (R7 structure) ----------------
// Only change vs R7: convW uses truncation-split (see header comment).
__global__ __launch_bounds__(256, 2)
void rec45_final_kernel(const u32* __restrict__ Yg, const float* __restrict__ W4,
                        const float* __restrict__ b4, const float* __restrict__ W5,
                        const float* __restrict__ b5, const float* __restrict__ wf,
                        const float* __restrict__ bff, float* __restrict__ out) {
    constexpr int LDW = 72;                 // window row stride (u16)
    __shared__ u16 Whi_w[64 * LDW];
    __shared__ u16 Wlo_w[64 * LDW];

    const int h = blockIdx.x;
    const int parent = ((h >> 5) << 3) | (h & 7);   // 0..255 = pgy*16+pgx
    const int child  = (h >> 3) & 3;
    const int pgy = parent >> 4, pgx = parent & 15;
    const int cy = 2 * pgy + (child >> 1), cx = 2 * pgx + (child & 1);
    const int bid5 = cy * 32 + cx;
    const int ocbase = child * 64;

    const u32* Yblk  = Yg + (size_t)parent * 65536;
    const float* W4s = W4 + (size_t)parent * 65536 + (size_t)ocbase * 256;
    const float* W5b = W5 + (size_t)bid5 * 65536;

    const int tid = threadIdx.x, wave = tid >> 6, lane = tid & 63;
    const int l16 = lane & 15, lk = lane >> 4;

    f32x4 acc1[4][4];
#pragma unroll
    for (int m = 0; m < 4; ++m)
#pragma unroll
        for (int n = 0; n < 4; ++n)
            acc1[m][n] = (f32x4){0.f, 0.f, 0.f, 0.f};

    u32    yf[2][4][8];
    float4 wv[2][8];
    bf16x8 wh[4], wl[4];

    auto loadY = [&](int buf, int k0) {
#pragma unroll
        for (int n = 0; n < 4; ++n)
#pragma unroll
            for (int j = 0; j < 8; ++j)
                yf[buf][n][j] = Yblk[(size_t)(k0 + 8 * lk + j) * 256 + wave * 64 + n * 16 + l16];
    };
    auto loadW4 = [&](int buf, int k0) {
#pragma unroll
        for (int m = 0; m < 4; ++m) {
            const float* p = W4s + (size_t)(m * 16 + l16) * 256 + k0 + lk * 8;
            wv[buf][2 * m]     = *(const float4*)p;
            wv[buf][2 * m + 1] = *(const float4*)(p + 4);
        }
    };
    auto loadW5 = [&](int buf, int t) {
#pragma unroll
        for (int m = 0; m < 4; ++m) {
            const float* p = W5b + (size_t)(wave * 64 + m * 16 + l16) * 256 + t * 32 + lk * 8;
            wv[buf][2 * m]     = *(const float4*)p;
            wv[buf][2 * m + 1] = *(const float4*)(p + 4);
        }
    };
    // Truncation-split: hi = bit-trunc(x) (top16), lo = trunc_bf16(x - hi).
    // x - hi is exact in f32; |x - (hi+lo)| <= 2^-16 |x|.
    auto convW = [&](int buf) {
#pragma unroll
        for (int m = 0; m < 4; ++m) {
            union { float4 f4[2]; u32 w[8]; } in;
            in.f4[0] = wv[buf][2 * m];
            in.f4[1] = wv[buf][2 * m + 1];
            union { u32 w[4]; bf16x8 v; } H, L;
#pragma unroll
            for (int j = 0; j < 4; ++j) {
                const u32 u0 = in.w[2 * j], u1 = in.w[2 * j + 1];
                const float x0 = __builtin_bit_cast(float, u0);
                const float x1 = __builtin_bit_cast(float, u1);
                const float h0 = __builtin_bit_cast(float, u0 & 0xFFFF0000u);
                const float h1 = __builtin_bit_cast(float, u1 & 0xFFFF0000u);
                const u32 l0 = __builtin_bit_cast(u32, x0 - h0);
                const u32 l1 = __builtin_bit_cast(u32, x1 - h1);
                H.w[j] = (u0 >> 16) | (u1 & 0xFFFF0000u);   // v_perm-able
                L.w[j] = (l0 >> 16) | (l1 & 0xFFFF0000u);
            }
            wh[m] = H.v;
            wl[m] = L.v;
        }
    };

    // ---- stage 1: no LDS, no barriers (R7 placement) ----
    loadY(0, 0); loadW4(0, 0); loadY(1, 32); loadW4(1, 32);
#pragma unroll
    for (int it = 0; it < 8; ++it) {
        const int cur = it & 1;
        convW(cur);
        __builtin_amdgcn_s_setprio(1);
#pragma unroll
        for (int n = 0; n < 4; ++n) {
            union { u32 w[4]; bf16x8 v; } BH, BL;
#pragma unroll
            for (int j = 0; j < 4; ++j) {
                const u32 y0 = yf[cur][n][2 * j], y1 = yf[cur][n][2 * j + 1];
                BH.w[j] = (y0 & 0xFFFFu) | (y1 << 16);
                BL.w[j] = (y0 >> 16)     | (y1 & 0xFFFF0000u);
            }
#pragma unroll
            for (int m = 0; m < 4; ++m)
                acc1[m][n] = __builtin_amdgcn_mfma_f32_16x16x32_bf16(wh[m], BH.v, acc1[m][n], 0, 0, 0);
#pragma unroll
            for (int m = 0; m < 4; ++m)
                acc1[m][n] = __builtin_amdgcn_mfma_f32_16x16x32_bf16(wh[m], BL.v, acc1[m][n], 0, 0, 0);
#pragma unroll
            for (int m = 0; m < 4; ++m)
                acc1[m][n] = __builtin_amdgcn_mfma_f32_16x16x32_bf16(wl[m], BH.v, acc1[m][n], 0, 0, 0);
        }
        __builtin_amdgcn_s_setprio(0);
        if (it + 2 < 8) { loadY(cur, 32 * it + 64); loadW4(cur, 32 * it + 64); }
    }

    // ---- stage 2: K-windows of 64 (window kw = acc1[kw]), R7 single-buffer ----
    f32x4 acc2[4][4];
#pragma unroll
    for (int m = 0; m < 4; ++m)
#pragma unroll
        for (int n = 0; n < 4; ++n)
            acc2[m][n] = (f32x4){0.f, 0.f, 0.f, 0.f};

    float b4v[4][4];
#pragma unroll
    for (int kw = 0; kw < 4; ++kw)
#pragma unroll
        for (int r = 0; r < 4; ++r)
            b4v[kw][r] = b4[(size_t)parent * 256 + ocbase + kw * 16 + lk * 4 + r];

    loadW5(0, 0); loadW5(1, 1);

#pragma unroll
    for (int kw = 0; kw < 4; ++kw) {
        // write window kw: k_global = i*4 + par, i = kw*16 + lk*4 + r
#pragma unroll
        for (int n = 0; n < 4; ++n) {
            const int colg = wave * 64 + n * 16 + l16;
            const int b_ = colg >> 2, par = colg & 3;
#pragma unroll
            for (int r = 0; r < 4; ++r) {
                const float v = fmaxf(acc1[kw][n][r] + b4v[kw][r], 0.f);
                const int k_ = lk * 16 + r * 4 + par;
                const u16 hh = bf16_rn(v);
                Whi_w[b_ * LDW + k_] = hh;
                Wlo_w[b_ * LDW + k_] = bf16_rn(v - bf16_to_f(hh));
            }
        }
        bar_lds();                       // window visible (global loads in flight)
#pragma unroll
        for (int kc = 0; kc < 2; ++kc) {
            const int t = kw * 2 + kc;
            const int cur = t & 1;
            convW(cur);                  // waits on W5 chunk t (issued 2 ago)
            __builtin_amdgcn_s_setprio(1);
#pragma unroll
            for (int n = 0; n < 4; ++n) {
                const int b_ = n * 16 + l16;
                const bf16x8 bhi = *(const bf16x8*)&Whi_w[b_ * LDW + kc * 32 + 8 * lk];
                const bf16x8 blo = *(const bf16x8*)&Wlo_w[b_ * LDW + kc * 32 + 8 * lk];
#pragma unroll
                for (int m = 0; m < 4; ++m)
                    acc2[m][n] = __builtin_amdgcn_mfma_f32_16x16x32_bf16(wh[m], bhi, acc2[m][n], 0, 0, 0);
#pragma unroll
                for (int m = 0; m < 4; ++m)
                    acc2[m][n] = __builtin_amdgcn_mfma_f32_16x16x32_bf16(wh[m], blo, acc2[m][n], 0, 0, 0);
#pragma unroll
                for (int m = 0; m < 4; ++m)
                    acc2[m][n] = __builtin_amdgcn_mfma_f32_16x16x32_bf16(wl[m], bhi, acc2[m][n], 0, 0, 0);
            }
            __builtin_amdgcn_s_setprio(0);
            if (t + 2 < 8) loadW5(cur, t + 2);
        }
        bar_lds();                       // reads of window kw done before next write
    }

    // ---- fused final: per-wave child block, within-wave reduce over channels ----
    const int fy = 2 * cy + (wave >> 1), fx = 2 * cx + (wave & 1);
    const int blk = fy * 64 + fx;
    float wf0v[4][4], wf2v[4][4], biv[4][4];
#pragma unroll
    for (int m = 0; m < 4; ++m)
#pragma unroll
        for (int r = 0; r < 4; ++r) {
            const int cch = m * 16 + lk * 4 + r;
            wf0v[m][r] = wf[(size_t)blk * 256 + cch];
            wf2v[m][r] = wf[(size_t)blk * 256 + 128 + cch];
            biv[m][r]  = b5[(size_t)bid5 * 256 + wave * 64 + cch];
        }
    const float bf0 = bff[blk * 4 + 0], bf2 = bff[blk * 4 + 2];
#pragma unroll
    for (int n = 0; n < 4; ++n) {
        float a0 = 0.f, a2 = 0.f;
#pragma unroll
        for (int m = 0; m < 4; ++m)
#pragma unroll
            for (int r = 0; r < 4; ++r) {
                const float y = fmaxf(acc2[m][n][r] + biv[m][r], 0.f);
                a0 = fmaf(y, wf0v[m][r], a0);
                a2 = fmaf(y, wf2v[m][r], a2);
            }
        a0 += __shfl_xor(a0, 16); a0 += __shfl_xor(a0, 32);
        a2 += __shfl_xor(a2, 16); a2 += __shfl_xor(a2, 32);
        if (lk == n) {
            const float o0 = fmaxf(a0 + bf0, 0.f);
            const float o2 = fmaxf(a2 + bf2, 0.f);
            out[(size_t)(n * 16 + l16) * 4096 + blk] = (o0 - o2) * (1.0f / 4096.0f);
        }
    }
}

extern "C" void kernel_launch(void* const* d_in, const int* in_sizes, int n_in,
                              void* d_out, int out_size, void* d_ws, size_t ws_size,
                              hipStream_t stream) {
    (void)in_sizes; (void)n_in; (void)out_size; (void)ws_size;

    const float* xr = (const float*)d_in[0];
    const float* xi = (const float*)d_in[1];
    const float* w0 = (const float*)d_in[2];
    const float* b0 = (const float*)d_in[3];
    const float* wrec[5] = { (const float*)d_in[4],  (const float*)d_in[6],
                             (const float*)d_in[8],  (const float*)d_in[10],
                             (const float*)d_in[12] };
    const float* brec[5] = { (const float*)d_in[5],  (const float*)d_in[7],
                             (const float*)d_in[9],  (const float*)d_in[11],
                             (const float*)d_in[13] };
    const float* wf = (const float*)d_in[14];
    const float* bf = (const float*)d_in[15];
    float* out = (float*)d_out;

    u32* bufA = (u32*)d_ws;
    u32* bufB = bufA + (size_t)PLANE;
    u16* wc1  = (u16*)(bufB + (size_t)PLANE);
    u16* wc2  = wc1 + (size_t)2 * 262144;
    u16* wc3  = wc2 + (size_t)2 * 1048576;

    wconv_all_kernel<<<2688, 256, 0, stream>>>(wrec[0], wrec[1], wrec[2], wc1, wc2, wc3);

    layer0_kernel<<<dim3(256, 2), 256, 0, stream>>>(xr, xi, w0, b0, bufA);

    // layer 1: G=2,  S2=16, Nb=16384
    rec_mfma_kernel<128><<<dim3(128, 1, 4), 256, 0, stream>>>(
        bufA, wc1, wc1 + 262144, brec[0], bufB, 1, 4);
    // layer 2: G=4,  S2=8,  Nb=4096
    rec_mfma_kernel<128><<<dim3(32, 1, 16), 256, 0, stream>>>(
        bufB, wc2, wc2 + 1048576, brec[1], bufA, 2, 3);
    // layer 3: G=8,  S2=4,  Nb=1024
    rec_mfma_kernel<128><<<dim3(8, 1, 64), 256, 0, stream>>>(
        bufA, wc3, wc3 + 4194304, brec[2], bufB, 3, 2);
    // layers 4+5+final fused: one wg per L5 block
    rec45_final_kernel<<<1024, 256, 0, stream>>>(
        bufB, wrec[3], brec[3], wrec[4], brec[4], wf, bf, out);
}

// Round 11
// 263.226 us; speedup vs baseline: 1.0903x; 1.0244x over previous
//
#include <hip/hip_runtime.h>
#include <cstddef>

// ButterFlyNet2D IDFT forward. Split-bf16 MFMA (3-pass: Whi*Yhi + Whi*Ylo + Wlo*Yhi).
// Activations: ONE u32 per element = packed (hi bf16 | lo bf16<<16).
//   Plane layout A[gy][gx][i][k][l][b][p][q] -> per block contiguous Y[256][Nb].
// R11 = R10 structure with wconv ELIMINATED: all layers load f32 W directly and
// trunc-split in-kernel (hi = bit-trunc, lo = trunc of exact remainder; proven
// precision-safe and time-free in R10). Same W bytes from L2 as the bf16-plane
// path; saves the 42 MB wconv round-trip + one launch.

typedef unsigned int  u32;
typedef unsigned short u16;
typedef __attribute__((ext_vector_type(8))) short bf16x8;
typedef __attribute__((ext_vector_type(4))) float f32x4;

#define PLANE 16777216   // elements per activation buffer

__device__ inline u16 bf16_rn(float x) {
    u32 u = __builtin_bit_cast(u32, x);
    u32 r = (u + 0x7FFFu + ((u >> 16) & 1u)) >> 16;
    return (u16)r;
}
__device__ inline float bf16_to_f(u16 h) {
    u32 u = ((u32)h) << 16;
    return __builtin_bit_cast(float, u);
}
__device__ inline u32 pack_split(float v) {
    const u16 h = bf16_rn(v);
    const u16 l = bf16_rn(v - bf16_to_f(h));
    return (u32)h | ((u32)l << 16);
}
// LDS-only barrier: drains ds ops, leaves global loads (vmcnt) in flight.
__device__ inline void bar_lds() {
    asm volatile("s_waitcnt lgkmcnt(0)\n\ts_barrier" ::: "memory");
}

// ---------------- Layer 0: x read once, 128 outputs per thread ----------------
__global__ __launch_bounds__(256)
void layer0_kernel(const float* __restrict__ xr, const float* __restrict__ xi,
                   const float* __restrict__ w0, const float* __restrict__ b0,
                   u32* __restrict__ A1) {
    __shared__ float w0s[128][16];
    __shared__ float b0s[128];
    const int og  = blockIdx.y;             // 0/1: o = og*128 + j
    const int tid = threadIdx.x;
    {
        const int row = tid >> 1, half = tid & 1;
        const float4 wa = *(const float4*)(w0 + (og * 128 + row) * 16 + half * 8);
        const float4 wb = *(const float4*)(w0 + (og * 128 + row) * 16 + half * 8 + 4);
        *(float4*)&w0s[row][half * 8]     = wa;
        *(float4*)&w0s[row][half * 8 + 4] = wb;
        if (tid < 128) b0s[tid] = b0[og * 128 + tid];
    }
    __syncthreads();

    const int n = blockIdx.x * 256 + tid;   // output pixel: b*1024 + p*32 + q
    const int b = n >> 10, p = (n >> 5) & 31, q = n & 31;
    float xs[16];
#pragma unroll
    for (int k = 0; k < 2; ++k) {
        const float2 vr = *(const float2*)(xr + b * 4096 + (2 * p + k) * 64 + 2 * q);
        const float2 vi = *(const float2*)(xi + b * 4096 + (2 * p + k) * 64 + 2 * q);
        xs[0  + k * 2 + 0] = fmaxf(vr.x, 0.f);  xs[0  + k * 2 + 1] = fmaxf(vr.y, 0.f);
        xs[4  + k * 2 + 0] = fmaxf(vi.x, 0.f);  xs[4  + k * 2 + 1] = fmaxf(vi.y, 0.f);
        xs[8  + k * 2 + 0] = fmaxf(-vr.x, 0.f); xs[8  + k * 2 + 1] = fmaxf(-vr.y, 0.f);
        xs[12 + k * 2 + 0] = fmaxf(-vi.x, 0.f); xs[12 + k * 2 + 1] = fmaxf(-vi.y, 0.f);
    }
    const int kp = p & 1, lp = q & 1, pp = p >> 1, qp = q >> 1;
    const size_t pixoff = (size_t)(b * 256 + pp * 16 + qp);
#pragma unroll
    for (int j = 0; j < 128; ++j) {
        float acc = b0s[j];
#pragma unroll
        for (int e = 0; e < 16; ++e) acc = fmaf(xs[e], w0s[j][e], acc);
        acc = fmaxf(acc, 0.f);
        const int o = og * 128 + j;
        const int gy = o >> 7, gx = (o >> 6) & 1, c = o & 63;
        const size_t flat = (size_t)((((gy * 2 + gx) * 64 + c) * 2 + kp) * 2 + lp) * (64 * 256)
                          + pixoff;
        A1[flat] = pack_split(acc);
    }
}

// ------- Recursion layers 1..3 : split-bf16 MFMA, W f32 direct + trunc-split -------
template<int NT>
__global__ __launch_bounds__(256, 2)
void rec_mfma_kernel(const u32* __restrict__ Yg, const float* __restrict__ Wf,
                     const float* __restrict__ bias, u32* __restrict__ Aout,
                     const int lgG, const int lgS2) {
    constexpr int NF  = NT / 16;
    constexpr int LD  = 40;
    constexpr int NCP = NT / 2;
    constexpr int RPT = 32 / (256 / NCP);

    __shared__ u16 Yhi_s[NT * LD];
    __shared__ u16 Ylo_s[NT * LD];

    const int G  = 1 << lgG;
    const int S2 = 1 << lgS2;
    const int Nb = 64 << (2 * lgS2);

    // XCD-chunked swizzle: keep all n-tiles of a block on one XCD (W L2 reuse)
    int bid, nt;
    const int nBid = G * G, NTILES = gridDim.x;
    if (nBid >= 8) {
        const int h = blockIdx.z * NTILES + blockIdx.x;
        const int xcd = h & 7, j = h >> 3, per = nBid >> 3;
        bid = xcd * per + j / NTILES;
        nt  = j % NTILES;
    } else { bid = blockIdx.z; nt = blockIdx.x; }

    const size_t wbase = (size_t)bid * 65536;
    const u32* Yblk = Yg + (size_t)bid * 256 * (size_t)Nb + (size_t)nt * NT;

    const int tid = threadIdx.x, wave = tid >> 6, lane = tid & 63;
    const int l16 = lane & 15, lk = lane >> 4;
    const int cp = tid % NCP, rg = tid / NCP;
    const int col0 = cp * 2, trow = rg * RPT;

    f32x4 acc[4][NF];
#pragma unroll
    for (int m = 0; m < 4; ++m)
#pragma unroll
        for (int n = 0; n < NF; ++n)
            acc[m][n] = (f32x4){0.f, 0.f, 0.f, 0.f};

    uint2  yreg[2][RPT];
    float4 wv[8];            // f32 W staging (single buffer, L2-hit latency)
    bf16x8 wh[4], wl[4];
    u32 yhw[2][RPT / 2], ylw[2][RPT / 2];

    auto loadY = [&](int ybuf, int k0) {
#pragma unroll
        for (int r = 0; r < RPT; ++r)
            yreg[ybuf][r] = *(const uint2*)(Yblk + (size_t)(k0 + trow + r) * Nb + col0);
    };
    auto loadWf32 = [&](int k0) {
#pragma unroll
        for (int m = 0; m < 4; ++m) {
            const float* p = Wf + wbase + (size_t)(wave * 64 + m * 16 + l16) * 256 + k0 + lk * 8;
            wv[2 * m]     = *(const float4*)p;
            wv[2 * m + 1] = *(const float4*)(p + 4);
        }
    };
    // trunc-split: hi = bit-trunc(x), lo = trunc_bf16(x - hi); x-hi exact.
    auto convW = [&]() {
#pragma unroll
        for (int m = 0; m < 4; ++m) {
            union { float4 f4[2]; u32 w[8]; } in;
            in.f4[0] = wv[2 * m];
            in.f4[1] = wv[2 * m + 1];
            union { u32 w[4]; bf16x8 v; } H, L;
#pragma unroll
            for (int j = 0; j < 4; ++j) {
                const u32 u0 = in.w[2 * j], u1 = in.w[2 * j + 1];
                const float x0 = __builtin_bit_cast(float, u0);
                const float x1 = __builtin_bit_cast(float, u1);
                const float h0 = __builtin_bit_cast(float, u0 & 0xFFFF0000u);
                const float h1 = __builtin_bit_cast(float, u1 & 0xFFFF0000u);
                const u32 l0 = __builtin_bit_cast(u32, x0 - h0);
                const u32 l1 = __builtin_bit_cast(u32, x1 - h1);
                H.w[j] = (u0 >> 16) | (u1 & 0xFFFF0000u);   // v_perm-able
                L.w[j] = (l0 >> 16) | (l1 & 0xFFFF0000u);
            }
            wh[m] = H.v;
            wl[m] = L.v;
        }
    };
    auto prepY = [&](int ybuf) {
#pragma unroll
        for (int c = 0; c < 2; ++c)
#pragma unroll
            for (int j2 = 0; j2 < RPT / 2; ++j2) {
                const u32 a = c ? yreg[ybuf][2 * j2].y     : yreg[ybuf][2 * j2].x;
                const u32 b = c ? yreg[ybuf][2 * j2 + 1].y : yreg[ybuf][2 * j2 + 1].x;
                yhw[c][j2] = (a & 0xFFFFu) | (b << 16);
                ylw[c][j2] = (a >> 16)     | (b & 0xFFFF0000u);
            }
    };
    auto stageY = [&]() {
#pragma unroll
        for (int c = 0; c < 2; ++c) {
            if constexpr (RPT == 8) {
                *(uint4*)&Yhi_s[(col0 + c) * LD + trow] = make_uint4(yhw[c][0], yhw[c][1], yhw[c][2], yhw[c][3]);
                *(uint4*)&Ylo_s[(col0 + c) * LD + trow] = make_uint4(ylw[c][0], ylw[c][1], ylw[c][2], ylw[c][3]);
            } else {
                *(uint2*)&Yhi_s[(col0 + c) * LD + trow] = make_uint2(yhw[c][0], yhw[c][1]);
                *(uint2*)&Ylo_s[(col0 + c) * LD + trow] = make_uint2(ylw[c][0], ylw[c][1]);
            }
        }
    };

    loadY(0, 0); loadY(1, 32);

#pragma unroll
    for (int it = 0; it < 8; ++it) {
        const int k0 = it * 32;
        const int cur = it & 1;
        loadWf32(k0);            // in flight across barriers (no vmcnt drain)
        prepY(cur);              // waits on yreg[cur] (issued 2 iters ago)
        bar_lds();               // prev MFMA ds_reads done; LDS reusable
        stageY();
        bar_lds();               // Y tile visible
        if (it + 2 < 8) loadY(cur, k0 + 64);
        convW();                 // waits on wv (issued before the barriers)
        __builtin_amdgcn_s_setprio(1);
#pragma unroll
        for (int n = 0; n < NF; ++n) {
            const int ccol = n * 16 + l16;
            const bf16x8 bhi = *(const bf16x8*)&Yhi_s[ccol * LD + 8 * lk];
            const bf16x8 blo = *(const bf16x8*)&Ylo_s[ccol * LD + 8 * lk];
#pragma unroll
            for (int m = 0; m < 4; ++m)
                acc[m][n] = __builtin_amdgcn_mfma_f32_16x16x32_bf16(wh[m], bhi, acc[m][n], 0, 0, 0);
#pragma unroll
            for (int m = 0; m < 4; ++m)
                acc[m][n] = __builtin_amdgcn_mfma_f32_16x16x32_bf16(wh[m], blo, acc[m][n], 0, 0, 0);
#pragma unroll
            for (int m = 0; m < 4; ++m)
                acc[m][n] = __builtin_amdgcn_mfma_f32_16x16x32_bf16(wl[m], bhi, acc[m][n], 0, 0, 0);
        }
        __builtin_amdgcn_s_setprio(0);
    }

    // ---- epilogue: bias + relu + packed scatter to child blocks ----
    const int gy = bid >> lgG, gx = bid & (G - 1);
    const int NS2 = S2 >> 1;
#pragma unroll
    for (int m = 0; m < 4; ++m) {
#pragma unroll
        for (int r = 0; r < 4; ++r) {
            const int oc = wave * 64 + m * 16 + lk * 4 + r;   // C/D: row=(lane>>4)*4+reg
            const float bi = bias[(size_t)bid * 256 + oc];
            const int yl = oc >> 7, xl = (oc >> 6) & 1, cch = oc & 63;
            const int cy = 2 * gy + yl, cx = 2 * gx + xl;
            const size_t base = (size_t)((cy * (2 * G) + cx) * 64 + cch);
#pragma unroll
            for (int n = 0; n < NF; ++n) {
                const float v = fmaxf(acc[m][n][r] + bi, 0.f);
                const int ng = nt * NT + n * 16 + l16;        // C/D: col=lane&15
                const int b   = ng >> (2 * lgS2);
                const int rem = ng & ((1 << (2 * lgS2)) - 1);
                const int p = rem >> lgS2, q = rem & (S2 - 1);
                const size_t flat = ((base * 2 + (p & 1)) * 2 + (q & 1)) * (size_t)(64 * NS2 * NS2)
                                  + (size_t)(b * NS2 * NS2 + (p >> 1) * NS2 + (q >> 1));
                Aout[flat] = pack_split(v);
            }
        }
    }
}

// ---------------- Fused L4 + L5 + final (R10 structure, unchanged) ----------------
__global__ __launch_bounds__(256, 2)
void rec45_final_kernel(const u32* __restrict__ Yg, const float* __restrict__ W4,
                        const float* __restrict__ b4, const float* __restrict__ W5,
                        const float* __restrict__ b5, const float* __restrict__ wf,
                        const float* __restrict__ bff, float* __restrict__ out) {
    constexpr int LDW = 72;                 // window row stride (u16)
    __shared__ u16 Whi_w[64 * LDW];
    __shared__ u16 Wlo_w[64 * LDW];

    const int h = blockIdx.x;
    const int parent = ((h >> 5) << 3) | (h & 7);   // 0..255 = pgy*16+pgx
    const int child  = (h >> 3) & 3;
    const int pgy = parent >> 4, pgx = parent & 15;
    const int cy = 2 * pgy + (child >> 1), cx = 2 * pgx + (child & 1);
    const int bid5 = cy * 32 + cx;
    const int ocbase = child * 64;

    const u32* Yblk  = Yg + (size_t)parent * 65536;
    const float* W4s = W4 + (size_t)parent * 65536 + (size_t)ocbase * 256;
    const float* W5b = W5 + (size_t)bid5 * 65536;

    const int tid = threadIdx.x, wave = tid >> 6, lane = tid & 63;
    const int l16 = lane & 15, lk = lane >> 4;

    f32x4 acc1[4][4];
#pragma unroll
    for (int m = 0; m < 4; ++m)
#pragma unroll
        for (int n = 0; n < 4; ++n)
            acc1[m][n] = (f32x4){0.f, 0.f, 0.f, 0.f};

    u32    yf[2][4][8];
    float4 wv[2][8];
    bf16x8 wh[4], wl[4];

    auto loadY = [&](int buf, int k0) {
#pragma unroll
        for (int n = 0; n < 4; ++n)
#pragma unroll
            for (int j = 0; j < 8; ++j)
                yf[buf][n][j] = Yblk[(size_t)(k0 + 8 * lk + j) * 256 + wave * 64 + n * 16 + l16];
    };
    auto loadW4 = [&](int buf, int k0) {
#pragma unroll
        for (int m = 0; m < 4; ++m) {
            const float* p = W4s + (size_t)(m * 16 + l16) * 256 + k0 + lk * 8;
            wv[buf][2 * m]     = *(const float4*)p;
            wv[buf][2 * m + 1] = *(const float4*)(p + 4);
        }
    };
    auto loadW5 = [&](int buf, int t) {
#pragma unroll
        for (int m = 0; m < 4; ++m) {
            const float* p = W5b + (size_t)(wave * 64 + m * 16 + l16) * 256 + t * 32 + lk * 8;
            wv[buf][2 * m]     = *(const float4*)p;
            wv[buf][2 * m + 1] = *(const float4*)(p + 4);
        }
    };
    auto convW = [&](int buf) {
#pragma unroll
        for (int m = 0; m < 4; ++m) {
            union { float4 f4[2]; u32 w[8]; } in;
            in.f4[0] = wv[buf][2 * m];
            in.f4[1] = wv[buf][2 * m + 1];
            union { u32 w[4]; bf16x8 v; } H, L;
#pragma unroll
            for (int j = 0; j < 4; ++j) {
                const u32 u0 = in.w[2 * j], u1 = in.w[2 * j + 1];
                const float x0 = __builtin_bit_cast(float, u0);
                const float x1 = __builtin_bit_cast(float, u1);
                const float h0 = __builtin_bit_cast(float, u0 & 0xFFFF0000u);
                const float h1 = __builtin_bit_cast(float, u1 & 0xFFFF0000u);
                const u32 l0 = __builtin_bit_cast(u32, x0 - h0);
                const u32 l1 = __builtin_bit_cast(u32, x1 - h1);
                H.w[j] = (u0 >> 16) | (u1 & 0xFFFF0000u);
                L.w[j] = (l0 >> 16) | (l1 & 0xFFFF0000u);
            }
            wh[m] = H.v;
            wl[m] = L.v;
        }
    };

    // ---- stage 1: no LDS, no barriers ----
    loadY(0, 0); loadW4(0, 0); loadY(1, 32); loadW4(1, 32);
#pragma unroll
    for (int it = 0; it < 8; ++it) {
        const int cur = it & 1;
        convW(cur);
        __builtin_amdgcn_s_setprio(1);
#pragma unroll
        for (int n = 0; n < 4; ++n) {
            union { u32 w[4]; bf16x8 v; } BH, BL;
#pragma unroll
            for (int j = 0; j < 4; ++j) {
                const u32 y0 = yf[cur][n][2 * j], y1 = yf[cur][n][2 * j + 1];
                BH.w[j] = (y0 & 0xFFFFu) | (y1 << 16);
                BL.w[j] = (y0 >> 16)     | (y1 & 0xFFFF0000u);
            }
#pragma unroll
            for (int m = 0; m < 4; ++m)
                acc1[m][n] = __builtin_amdgcn_mfma_f32_16x16x32_bf16(wh[m], BH.v, acc1[m][n], 0, 0, 0);
#pragma unroll
            for (int m = 0; m < 4; ++m)
                acc1[m][n] = __builtin_amdgcn_mfma_f32_16x16x32_bf16(wh[m], BL.v, acc1[m][n], 0, 0, 0);
#pragma unroll
            for (int m = 0; m < 4; ++m)
                acc1[m][n] = __builtin_amdgcn_mfma_f32_16x16x32_bf16(wl[m], BH.v, acc1[m][n], 0, 0, 0);
        }
        __builtin_amdgcn_s_setprio(0);
        if (it + 2 < 8) { loadY(cur, 32 * it + 64); loadW4(cur, 32 * it + 64); }
    }

    // ---- stage 2: K-windows of 64 (window kw = acc1[kw]) ----
    f32x4 acc2[4][4];
#pragma unroll
    for (int m = 0; m < 4; ++m)
#pragma unroll
        for (int n = 0; n < 4; ++n)
            acc2[m][n] = (f32x4){0.f, 0.f, 0.f, 0.f};

    float b4v[4][4];
#pragma unroll
    for (int kw = 0; kw < 4; ++kw)
#pragma unroll
        for (int r = 0; r < 4; ++r)
            b4v[kw][r] = b4[(size_t)parent * 256 + ocbase + kw * 16 + lk * 4 + r];

    loadW5(0, 0); loadW5(1, 1);

#pragma unroll
    for (int kw = 0; kw < 4; ++kw) {
        // write window kw: k_global = i*4 + par, i = kw*16 + lk*4 + r
#pragma unroll
        for (int n = 0; n < 4; ++n) {
            const int colg = wave * 64 + n * 16 + l16;
            const int b_ = colg >> 2, par = colg & 3;
#pragma unroll
            for (int r = 0; r < 4; ++r) {
                const float v = fmaxf(acc1[kw][n][r] + b4v[kw][r], 0.f);
                const int k_ = lk * 16 + r * 4 + par;
                const u16 hh = bf16_rn(v);
                Whi_w[b_ * LDW + k_] = hh;
                Wlo_w[b_ * LDW + k_] = bf16_rn(v - bf16_to_f(hh));
            }
        }
        bar_lds();                       // window visible (global loads in flight)
#pragma unroll
        for (int kc = 0; kc < 2; ++kc) {
            const int t = kw * 2 + kc;
            const int cur = t & 1;
            convW(cur);                  // waits on W5 chunk t (issued 2 ago)
            __builtin_amdgcn_s_setprio(1);
#pragma unroll
            for (int n = 0; n < 4; ++n) {
                const int b_ = n * 16 + l16;
                const bf16x8 bhi = *(const bf16x8*)&Whi_w[b_ * LDW + kc * 32 + 8 * lk];
                const bf16x8 blo = *(const bf16x8*)&Wlo_w[b_ * LDW + kc * 32 + 8 * lk];
#pragma unroll
                for (int m = 0; m < 4; ++m)
                    acc2[m][n] = __builtin_amdgcn_mfma_f32_16x16x32_bf16(wh[m], bhi, acc2[m][n], 0, 0, 0);
#pragma unroll
                for (int m = 0; m < 4; ++m)
                    acc2[m][n] = __builtin_amdgcn_mfma_f32_16x16x32_bf16(wh[m], blo, acc2[m][n], 0, 0, 0);
#pragma unroll
                for (int m = 0; m < 4; ++m)
                    acc2[m][n] = __builtin_amdgcn_mfma_f32_16x16x32_bf16(wl[m], bhi, acc2[m][n], 0, 0, 0);
            }
            __builtin_amdgcn_s_setprio(0);
            if (t + 2 < 8) loadW5(cur, t + 2);
        }
        bar_lds();                       // reads of window kw done before next write
    }

    // ---- fused final: per-wave child block, within-wave reduce over channels ----
    const int fy = 2 * cy + (wave >> 1), fx = 2 * cx + (wave & 1);
    const int blk = fy * 64 + fx;
    float wf0v[4][4], wf2v[4][4], biv[4][4];
#pragma unroll
    for (int m = 0; m < 4; ++m)
#pragma unroll
        for (int r = 0; r < 4; ++r) {
            const int cch = m * 16 + lk * 4 + r;
            wf0v[m][r] = wf[(size_t)blk * 256 + cch];
            wf2v[m][r] = wf[(size_t)blk * 256 + 128 + cch];
            biv[m][r]  = b5[(size_t)bid5 * 256 + wave * 64 + cch];
        }
    const float bf0 = bff[blk * 4 + 0], bf2 = bff[blk * 4 + 2];
#pragma unroll
    for (int n = 0; n < 4; ++n) {
        float a0 = 0.f, a2 = 0.f;
#pragma unroll
        for (int m = 0; m < 4; ++m)
#pragma unroll
            for (int r = 0; r < 4; ++r) {
                const float y = fmaxf(acc2[m][n][r] + biv[m][r], 0.f);
                a0 = fmaf(y, wf0v[m][r], a0);
                a2 = fmaf(y, wf2v[m][r], a2);
            }
        a0 += __shfl_xor(a0, 16); a0 += __shfl_xor(a0, 32);
        a2 += __shfl_xor(a2, 16); a2 += __shfl_xor(a2, 32);
        if (lk == n) {
            const float o0 = fmaxf(a0 + bf0, 0.f);
            const float o2 = fmaxf(a2 + bf2, 0.f);
            out[(size_t)(n * 16 + l16) * 4096 + blk] = (o0 - o2) * (1.0f / 4096.0f);
        }
    }
}

extern "C" void kernel_launch(void* const* d_in, const int* in_sizes, int n_in,
                              void* d_out, int out_size, void* d_ws, size_t ws_size,
                              hipStream_t stream) {
    (void)in_sizes; (void)n_in; (void)out_size; (void)ws_size;

    const float* xr = (const float*)d_in[0];
    const float* xi = (const float*)d_in[1];
    const float* w0 = (const float*)d_in[2];
    const float* b0 = (const float*)d_in[3];
    const float* wrec[5] = { (const float*)d_in[4],  (const float*)d_in[6],
                             (const float*)d_in[8],  (const float*)d_in[10],
                             (const float*)d_in[12] };
    const float* brec[5] = { (const float*)d_in[5],  (const float*)d_in[7],
                             (const float*)d_in[9],  (const float*)d_in[11],
                             (const float*)d_in[13] };
    const float* wf = (const float*)d_in[14];
    const float* bf = (const float*)d_in[15];
    float* out = (float*)d_out;

    u32* bufA = (u32*)d_ws;
    u32* bufB = bufA + (size_t)PLANE;

    layer0_kernel<<<dim3(256, 2), 256, 0, stream>>>(xr, xi, w0, b0, bufA);

    // layer 1: G=2,  S2=16, Nb=16384
    rec_mfma_kernel<128><<<dim3(128, 1, 4), 256, 0, stream>>>(
        bufA, wrec[0], brec[0], bufB, 1, 4);
    // layer 2: G=4,  S2=8,  Nb=4096
    rec_mfma_kernel<128><<<dim3(32, 1, 16), 256, 0, stream>>>(
        bufB, wrec[1], brec[1], bufA, 2, 3);
    // layer 3: G=8,  S2=4,  Nb=1024
    rec_mfma_kernel<128><<<dim3(8, 1, 64), 256, 0, stream>>>(
        bufA, wrec[2], brec[2], bufB, 3, 2);
    // layers 4+5+final fused: one wg per L5 block
    rec45_final_kernel<<<1024, 256, 0, stream>>>(
        bufB, wrec[3], brec[3], wrec[4], brec[4], wf, bf, out);
}